// Round 1
// baseline (650.383 us; speedup 1.0000x reference)
//
#include <hip/hip_runtime.h>

typedef unsigned short us;
typedef unsigned int u32;
typedef __attribute__((ext_vector_type(8))) short short8;
typedef __attribute__((ext_vector_type(4))) float f32x4;

#define MFMA16(a, b, c) __builtin_amdgcn_mfma_f32_16x16x32_bf16((a), (b), (c), 0, 0, 0)

// async global->LDS, 16B per lane; lds ptr must be wave-uniform
#define GLD16(lptr, gptr) __builtin_amdgcn_global_load_lds( \
    (__attribute__((address_space(1))) void*)(gptr), \
    (__attribute__((address_space(3))) void*)(lptr), 16, 0, 0)

// ---- bf16 split helpers (RNE via bit trick; no NaN inputs here) ----
__device__ inline us f2bf(float f) {
  u32 u = __float_as_uint(f);
  u32 r = (u + 0x7FFFu + ((u >> 16) & 1u)) >> 16;
  return (us)r;
}
__device__ inline float bf2f(us s) { return __uint_as_float((u32)s << 16); }
__device__ inline void splitbf(float x, us& hi, us& lo) {
  hi = f2bf(x);
  lo = f2bf(x - bf2f(hi));
}

// ================= init small accumulators =================
__global__ void k_init(float* accs) {  // [0]=ent, [1]=ce, [2..66]=mean_p
  int t = threadIdx.x;
  if (t < 67) accs[t] = 0.f;
}

// ================= dropout mask: JAX threefry2x32, key (0,42) =================
#define TF_R(a) { x0 += x1; x1 = (x1 << (a)) | (x1 >> (32 - (a))); x1 ^= x0; }
__global__ void k_mask(u32* __restrict__ mask) {
  u32 t = blockIdx.x * 256u + threadIdx.x;  // 0..131071
  const u32 K0 = 0u, K1 = 42u, K2 = 0x1BD11BDAu ^ 0u ^ 42u;
  u32 w0 = 0, w1 = 0;
  for (int i = 0; i < 32; ++i) {
    u32 x0 = t * 32u + (u32)i;
    u32 x1 = x0 + 4194304u;
    x0 += K0; x1 += K1;
    TF_R(13) TF_R(15) TF_R(26) TF_R(6)   x0 += K1; x1 += K2 + 1u;
    TF_R(17) TF_R(29) TF_R(16) TF_R(24)  x0 += K2; x1 += K0 + 2u;
    TF_R(13) TF_R(15) TF_R(26) TF_R(6)   x0 += K0; x1 += K1 + 3u;
    TF_R(17) TF_R(29) TF_R(16) TF_R(24)  x0 += K1; x1 += K2 + 4u;
    TF_R(13) TF_R(15) TF_R(26) TF_R(6)   x0 += K2; x1 += K0 + 5u;
    w0 |= (u32)((x0 >> 31) == 0u) << i;  // uniform<0.5  <=>  top bit 0
    w1 |= (u32)((x1 >> 31) == 0u) << i;
  }
  mask[t] = w0;
  mask[t + 131072u] = w1;
}

// ================= split+transpose w1 [2048][512] -> w1t planes [512][2048] =================
__global__ void k_splitw1(const float* __restrict__ w1, us* __restrict__ th, us* __restrict__ tl) {
  __shared__ float tile[64][65];
  int k0 = blockIdx.x * 64, n0 = blockIdx.y * 64;
  int t = threadIdx.x;
  int cr = t >> 6, cc = t & 63;
  for (int i = 0; i < 16; ++i) {
    int r = i * 4 + cr;
    tile[r][cc] = w1[(size_t)(k0 + r) * 512 + n0 + cc];
  }
  __syncthreads();
  for (int i = 0; i < 16; ++i) {
    int n = i * 4 + cr;
    int k = cc;
    us hi, lo; splitbf(tile[k][n], hi, lo);
    size_t o = (size_t)(n0 + n) * 2048 + k0 + k;
    th[o] = hi; tl[o] = lo;
  }
}

// ================= split+transpose w2 [512][65] -> w2t planes [80][512] (pad zero) =================
__global__ void k_splitw2(const float* __restrict__ w2, us* __restrict__ th, us* __restrict__ tl) {
  int n = blockIdx.x;  // 0..79
  for (int k = threadIdx.x; k < 512; k += 256) {
    float v = (n < 65) ? w2[(size_t)k * 65 + n] : 0.f;
    us hi, lo; splitbf(v, hi, lo);
    th[n * 512 + k] = hi; tl[n * 512 + k] = lo;
  }
}

// ================= split feat fp32 -> hi/lo bf16 planes =================
__global__ void k_splitfeat(const float* __restrict__ x, us* __restrict__ xh, us* __restrict__ xl) {
  size_t g = ((size_t)blockIdx.x * 256 + threadIdx.x) * 8;
  f32x4 a = *(const f32x4*)(x + g);
  f32x4 b = *(const f32x4*)(x + g + 4);
  short8 h8, l8;
  for (int i = 0; i < 4; ++i) {
    us hi, lo;
    splitbf(a[i], hi, lo); h8[i] = (short)hi; l8[i] = (short)lo;
    splitbf(b[i], hi, lo); h8[4 + i] = (short)hi; l8[4 + i] = (short)lo;
  }
  *(short8*)(xh + g) = h8;
  *(short8*)(xl + g) = l8;
}

// ================= GEMM1: h = dropout(relu(feat@w1 + b1)), bf16x3, 128x128x32 =================
__global__ __launch_bounds__(256, 2) void k_gemm1(
    const us* __restrict__ Ah_, const us* __restrict__ Al_,   // feat planes [16384][2048]
    const us* __restrict__ Bh_, const us* __restrict__ Bl_,   // w1t planes  [512][2048]
    const float* __restrict__ b1, const u32* __restrict__ mask,
    us* __restrict__ Hh, us* __restrict__ Hl) {
  __shared__ __align__(16) us lds[4 * 4096];  // Ah, Al, Bh, Bl tiles [128][32]
  us* sAh = lds; us* sAl = lds + 4096; us* sBh = lds + 8192; us* sBl = lds + 12288;
  int tid = threadIdx.x;
  int bn = blockIdx.x, bm = blockIdx.y;
  int m0 = bm * 128, n0 = bn * 128;
  int lane = tid & 63, wv = tid >> 6;
  int wm = (wv >> 1) * 64, wn = (wv & 1) * 64;
  int frow = lane & 15, fk = (lane >> 4) * 8;
  int srow = tid >> 2, scol = (tid & 3) * 8;
  f32x4 acc[4][4] = {};
  size_t arow = (size_t)(m0 + srow) * 2048 + scol;
  size_t brow = (size_t)(n0 + srow) * 2048 + scol;
  for (int kt = 0; kt < 64; ++kt) {
    int k0 = kt * 32;
    __syncthreads();
    GLD16(sAh + wv * 512,        Ah_ + arow + k0);
    GLD16(sAh + 2048 + wv * 512, Ah_ + arow + (size_t)64 * 2048 + k0);
    GLD16(sAl + wv * 512,        Al_ + arow + k0);
    GLD16(sAl + 2048 + wv * 512, Al_ + arow + (size_t)64 * 2048 + k0);
    GLD16(sBh + wv * 512,        Bh_ + brow + k0);
    GLD16(sBh + 2048 + wv * 512, Bh_ + brow + (size_t)64 * 2048 + k0);
    GLD16(sBl + wv * 512,        Bl_ + brow + k0);
    GLD16(sBl + 2048 + wv * 512, Bl_ + brow + (size_t)64 * 2048 + k0);
    __syncthreads();
    short8 ah[4], al[4], bh[4], bl[4];
#pragma unroll
    for (int f = 0; f < 4; ++f) {
      ah[f] = *(const short8*)&sAh[(wm + f * 16 + frow) * 32 + fk];
      al[f] = *(const short8*)&sAl[(wm + f * 16 + frow) * 32 + fk];
      bh[f] = *(const short8*)&sBh[(wn + f * 16 + frow) * 32 + fk];
      bl[f] = *(const short8*)&sBl[(wn + f * 16 + frow) * 32 + fk];
    }
#pragma unroll
    for (int i = 0; i < 4; ++i)
#pragma unroll
      for (int j = 0; j < 4; ++j) {
        acc[i][j] = MFMA16(ah[i], bh[j], acc[i][j]);
        acc[i][j] = MFMA16(ah[i], bl[j], acc[i][j]);
        acc[i][j] = MFMA16(al[i], bh[j], acc[i][j]);
      }
  }
  // epilogue: +b1, relu, dropout, split to bf16 hi/lo
#pragma unroll
  for (int i = 0; i < 4; ++i)
#pragma unroll
    for (int j = 0; j < 4; ++j)
#pragma unroll
      for (int r = 0; r < 4; ++r) {
        int row = m0 + wm + i * 16 + (lane >> 4) * 4 + r;
        int col = n0 + wn + j * 16 + (lane & 15);
        float v = acc[i][j][r] + b1[col];
        v = fmaxf(v, 0.f);
        u32 f = (u32)row * 512u + (u32)col;
        u32 keep = (mask[f >> 5] >> (f & 31u)) & 1u;
        v = keep ? v * 2.f : 0.f;
        us hi, lo; splitbf(v, hi, lo);
        size_t o = (size_t)row * 512 + col;
        Hh[o] = hi; Hl[o] = lo;
      }
}

// ================= GEMM2 (64x80, K=512) + fused softmax stats =================
__global__ __launch_bounds__(256, 2) void k_gemm2(
    const us* __restrict__ Ah_, const us* __restrict__ Al_,   // h planes [16384][512]
    const us* __restrict__ Bh_, const us* __restrict__ Bl_,   // w2t planes [80][512]
    const float* __restrict__ b2,
    float* __restrict__ logp, int* __restrict__ preds,
    float* __restrict__ accs /* [0] ent, [2..] mp */) {
  __shared__ __align__(16) us sA[2][2048];   // [64][32] hi/lo
  __shared__ __align__(16) us sB[2][2560];   // [80][32] hi/lo
  __shared__ float slog[64 * 81];
  __shared__ float sm[64], sl[64];
  __shared__ float sred[256];
  int tid = threadIdx.x;
  int m0 = blockIdx.x * 64;
  int lane = tid & 63, wv = tid >> 6;
  int frow = lane & 15, fk = (lane >> 4) * 8;
  int srow = tid >> 2, scol = (tid & 3) * 8;
  int r2 = 64 + (lane >> 2), sc2 = (lane & 3) * 8;
  f32x4 acc[5] = {};
  size_t arow = (size_t)(m0 + srow) * 512 + scol;
  size_t brow = (size_t)srow * 512 + scol;
  size_t brow2 = (size_t)r2 * 512 + sc2;
  for (int kt = 0; kt < 16; ++kt) {
    int k0 = kt * 32;
    __syncthreads();
    GLD16(&sA[0][wv * 512], Ah_ + arow + k0);
    GLD16(&sA[1][wv * 512], Al_ + arow + k0);
    GLD16(&sB[0][wv * 512], Bh_ + brow + k0);
    GLD16(&sB[1][wv * 512], Bl_ + brow + k0);
    if (wv == 0) {
      GLD16(&sB[0][2048], Bh_ + brow2 + k0);
      GLD16(&sB[1][2048], Bl_ + brow2 + k0);
    }
    __syncthreads();
    short8 a_h = *(const short8*)&sA[0][(wv * 16 + frow) * 32 + fk];
    short8 a_l = *(const short8*)&sA[1][(wv * 16 + frow) * 32 + fk];
#pragma unroll
    for (int fn = 0; fn < 5; ++fn) {
      short8 b_h = *(const short8*)&sB[0][(fn * 16 + frow) * 32 + fk];
      short8 b_l = *(const short8*)&sB[1][(fn * 16 + frow) * 32 + fk];
      acc[fn] = MFMA16(a_h, b_h, acc[fn]);
      acc[fn] = MFMA16(a_h, b_l, acc[fn]);
      acc[fn] = MFMA16(a_l, b_h, acc[fn]);
    }
  }
  // logits -> LDS (+bias)
#pragma unroll
  for (int fn = 0; fn < 5; ++fn) {
    int col = fn * 16 + (lane & 15);
    if (col < 65) {
      float bb = b2[col];
#pragma unroll
      for (int r = 0; r < 4; ++r) {
        int row = wv * 16 + (lane >> 4) * 4 + r;
        slog[row * 81 + col] = acc[fn][r] + bb;
      }
    }
  }
  __syncthreads();
  if (tid < 64) {
    int row = tid;
    float m = -1e30f; int am = 0;
    for (int c = 0; c < 65; ++c) {
      float v = slog[row * 81 + c];
      if (v > m) { m = v; am = c; }   // first-max: strict >
    }
    float s = 0.f;
    for (int c = 0; c < 65; ++c) s += expf(slog[row * 81 + c] - m);
    sm[row] = m; sl[row] = logf(s);
    preds[m0 + row] = am;
  }
  __syncthreads();
  float entp = 0.f;
  if (tid < 240) {
    int c = tid % 80, rr0 = tid / 80;
    if (c < 65) {
      float mpp = 0.f;
      for (int r = rr0; r < 64; r += 3) {
        float v = slog[r * 81 + c] - sm[r] - sl[r];
        logp[(size_t)(m0 + r) * 65 + c] = v;
        float p = expf(v);
        mpp += p;
        entp += p * logf(p + 1e-6f);
      }
      atomicAdd(&accs[2 + c], mpp);
    }
  }
  sred[tid] = entp;
  __syncthreads();
  for (int s = 128; s > 0; s >>= 1) { if (tid < s) sred[tid] += sred[tid + s]; __syncthreads(); }
  if (tid == 0) atomicAdd(&accs[0], sred[0]);
}

// ================= segment sums of feat by pred =================
__global__ __launch_bounds__(256) void k_segsum(
    const float* __restrict__ feat, const int* __restrict__ preds,
    float* __restrict__ psum, int* __restrict__ pcnt) {
  int dc = blockIdx.x;  // 0..31 (64 cols each)
  int nc = blockIdx.y;  // 0..15 (1024 rows each)
  __shared__ float acc[65 * 64];
  __shared__ int pl[1024];
  int tid = threadIdx.x;
  for (int i = tid; i < 65 * 64; i += 256) acc[i] = 0.f;
  int r0 = nc * 1024;
  for (int i = tid; i < 1024; i += 256) pl[i] = preds[r0 + i];
  __syncthreads();
  int lane = tid & 63, wv = tid >> 6;
  int col = dc * 64 + lane;
  for (int r = wv; r < 1024; r += 4) {
    int c = pl[r];
    float x = feat[(size_t)(r0 + r) * 2048 + col];
    atomicAdd(&acc[c * 64 + lane], x);   // ds_add_f32
  }
  __syncthreads();
  for (int i = tid; i < 65 * 64; i += 256) {
    int c = i >> 6, l = i & 63;
    psum[((size_t)nc * 65 + c) * 2048 + dc * 64 + l] = acc[i];
  }
  if (dc == 0 && tid < 65) {
    int cnt = 0;
    for (int r = 0; r < 1024; ++r) cnt += (pl[r] == tid);
    pcnt[nc * 65 + tid] = cnt;
  }
}

// ================= centroids: reduce partials, normalize, split bf16; B^T layout [80][2048] =================
__global__ __launch_bounds__(256) void k_centroid(
    const float* __restrict__ psum, const int* __restrict__ pcnt,
    us* __restrict__ ch, us* __restrict__ cl) {
  int c = blockIdx.x;  // 0..79
  int tid = threadIdx.x;
  if (c >= 65) {
    for (int d = tid; d < 2048; d += 256) { ch[(size_t)c * 2048 + d] = 0; cl[(size_t)c * 2048 + d] = 0; }
    return;
  }
  int cnt = 0;
  for (int nc = 0; nc < 16; ++nc) cnt += pcnt[nc * 65 + c];
  float inv = 1.0f / (float)((cnt > 1) ? cnt : 1);
  float mean[8]; float sq = 0.f;
  for (int i = 0; i < 8; ++i) {
    int d = tid + i * 256;
    float s = 0.f;
    for (int nc = 0; nc < 16; ++nc) s += psum[((size_t)nc * 65 + c) * 2048 + d];
    mean[i] = s * inv;
    sq += mean[i] * mean[i];
  }
  __shared__ float red[256];
  red[tid] = sq; __syncthreads();
  for (int s = 128; s > 0; s >>= 1) { if (tid < s) red[tid] += red[tid + s]; __syncthreads(); }
  float norm = sqrtf(red[0]);
  float dscale = (cnt > 0) ? 1.0f / fmaxf(norm, 1e-12f) : 0.0f;
  for (int i = 0; i < 8; ++i) {
    int d = tid + i * 256;
    us hi, lo; splitbf(mean[i] * dscale, hi, lo);
    ch[(size_t)c * 2048 + d] = hi; cl[(size_t)c * 2048 + d] = lo;
  }
}

// ================= sim GEMM (64x80, K=2048) + argmax + CE gather =================
__global__ __launch_bounds__(256, 2) void k_sim(
    const us* __restrict__ Ah_, const us* __restrict__ Al_,   // feat planes [16384][2048]
    const us* __restrict__ Bh_, const us* __restrict__ Bl_,   // cent planes [80][2048]
    const float* __restrict__ logp, float* __restrict__ accs /* [1]=ce */) {
  __shared__ __align__(16) us sA[2][2048];
  __shared__ __align__(16) us sB[2][2560];
  __shared__ float ssim[64 * 81];
  __shared__ float sred[256];
  int tid = threadIdx.x;
  int m0 = blockIdx.x * 64;
  int lane = tid & 63, wv = tid >> 6;
  int frow = lane & 15, fk = (lane >> 4) * 8;
  int srow = tid >> 2, scol = (tid & 3) * 8;
  int r2 = 64 + (lane >> 2), sc2 = (lane & 3) * 8;
  f32x4 acc[5] = {};
  size_t arow = (size_t)(m0 + srow) * 2048 + scol;
  size_t brow = (size_t)srow * 2048 + scol;
  size_t brow2 = (size_t)r2 * 2048 + sc2;
  for (int kt = 0; kt < 64; ++kt) {
    int k0 = kt * 32;
    __syncthreads();
    GLD16(&sA[0][wv * 512], Ah_ + arow + k0);
    GLD16(&sA[1][wv * 512], Al_ + arow + k0);
    GLD16(&sB[0][wv * 512], Bh_ + brow + k0);
    GLD16(&sB[1][wv * 512], Bl_ + brow + k0);
    if (wv == 0) {
      GLD16(&sB[0][2048], Bh_ + brow2 + k0);
      GLD16(&sB[1][2048], Bl_ + brow2 + k0);
    }
    __syncthreads();
    short8 a_h = *(const short8*)&sA[0][(wv * 16 + frow) * 32 + fk];
    short8 a_l = *(const short8*)&sA[1][(wv * 16 + frow) * 32 + fk];
#pragma unroll
    for (int fn = 0; fn < 5; ++fn) {
      short8 b_h = *(const short8*)&sB[0][(fn * 16 + frow) * 32 + fk];
      short8 b_l = *(const short8*)&sB[1][(fn * 16 + frow) * 32 + fk];
      acc[fn] = MFMA16(a_h, b_h, acc[fn]);
      acc[fn] = MFMA16(a_h, b_l, acc[fn]);
      acc[fn] = MFMA16(a_l, b_h, acc[fn]);
    }
  }
#pragma unroll
  for (int fn = 0; fn < 5; ++fn) {
    int col = fn * 16 + (lane & 15);
    if (col < 65)
#pragma unroll
      for (int r = 0; r < 4; ++r)
        ssim[(wv * 16 + (lane >> 4) * 4 + r) * 81 + col] = acc[fn][r];
  }
  __syncthreads();
  float cep = 0.f;
  if (tid < 64) {
    float m = -1e30f; int am = 0;
    for (int c = 0; c < 65; ++c) {
      float v = ssim[tid * 81 + c];
      if (v > m) { m = v; am = c; }
    }
    cep = logp[(size_t)(m0 + tid) * 65 + am];
  }
  sred[tid] = cep;
  __syncthreads();
  for (int s = 128; s > 0; s >>= 1) { if (tid < s) sred[tid] += sred[tid + s]; __syncthreads(); }
  if (tid == 0) atomicAdd(&accs[1], sred[0]);
}

// ================= final combine =================
__global__ void k_final(const float* __restrict__ accs, float* __restrict__ out) {
  __shared__ float red[256];
  int t = threadIdx.x;
  float d = 0.f;
  if (t < 65) {
    float mp = accs[2 + t] * (1.f / 16384.f);
    d = mp * logf(mp + 1e-6f);
  }
  red[t] = d; __syncthreads();
  for (int s = 128; s > 0; s >>= 1) { if (t < s) red[t] += red[t + s]; __syncthreads(); }
  if (t == 0) {
    float entropy = -accs[0] * (1.f / 16384.f);
    float ce = -accs[1] * (1.f / 16384.f);
    out[0] = entropy + red[0] + 0.3f * ce;
  }
}

extern "C" void kernel_launch(void* const* d_in, const int* in_sizes, int n_in,
                              void* d_out, int out_size, void* d_ws, size_t ws_size,
                              hipStream_t stream) {
  const float* feat = (const float*)d_in[0];
  const float* w1   = (const float*)d_in[1];
  const float* b1   = (const float*)d_in[2];
  const float* w2   = (const float*)d_in[3];
  const float* b2   = (const float*)d_in[4];
  float* out = (float*)d_out;

  char* w = (char*)d_ws;
  auto alloc = [&](size_t b) { char* p = w; w += (b + 255) & ~(size_t)255; return p; };
  us*  feat_hi = (us*)alloc(16384ull * 2048 * 2);
  us*  feat_lo = (us*)alloc(16384ull * 2048 * 2);
  us*  w1t_hi  = (us*)alloc(512ull * 2048 * 2);
  us*  w1t_lo  = (us*)alloc(512ull * 2048 * 2);
  us*  w2t_hi  = (us*)alloc(80ull * 512 * 2);
  us*  w2t_lo  = (us*)alloc(80ull * 512 * 2);
  u32* mask    = (u32*)alloc(262144ull * 4);
  us*  h_hi    = (us*)alloc(16384ull * 512 * 2);
  us*  h_lo    = (us*)alloc(16384ull * 512 * 2);
  float* logp  = (float*)alloc(16384ull * 65 * 4);
  int*   preds = (int*)alloc(16384ull * 4);
  float* psum  = (float*)alloc(16ull * 65 * 2048 * 4);
  int*   pcnt  = (int*)alloc(16ull * 65 * 4);
  us*  cent_hi = (us*)alloc(80ull * 2048 * 2);
  us*  cent_lo = (us*)alloc(80ull * 2048 * 2);
  float* accs  = (float*)alloc(68ull * 4);

  k_init<<<1, 256, 0, stream>>>(accs);
  k_mask<<<512, 256, 0, stream>>>(mask);
  k_splitw1<<<dim3(32, 8), 256, 0, stream>>>(w1, w1t_hi, w1t_lo);
  k_splitw2<<<80, 256, 0, stream>>>(w2, w2t_hi, w2t_lo);
  k_splitfeat<<<16384, 256, 0, stream>>>(feat, feat_hi, feat_lo);
  k_gemm1<<<dim3(4, 128), 256, 0, stream>>>(feat_hi, feat_lo, w1t_hi, w1t_lo, b1, mask, h_hi, h_lo);
  k_gemm2<<<256, 256, 0, stream>>>(h_hi, h_lo, w2t_hi, w2t_lo, b2, logp, preds, accs);
  k_segsum<<<dim3(32, 16), 256, 0, stream>>>(feat, preds, psum, pcnt);
  k_centroid<<<80, 256, 0, stream>>>(psum, pcnt, cent_hi, cent_lo);
  k_sim<<<256, 256, 0, stream>>>(feat_hi, feat_lo, cent_hi, cent_lo, logp, accs);
  k_final<<<1, 256, 0, stream>>>(accs, out);
}

// Round 2
// 560.326 us; speedup vs baseline: 1.1607x; 1.1607x over previous
//
#include <hip/hip_runtime.h>

typedef unsigned short us;
typedef unsigned int u32;
typedef __attribute__((ext_vector_type(8))) short short8;
typedef __attribute__((ext_vector_type(4))) float f32x4;

#define MFMA16(a, b, c) __builtin_amdgcn_mfma_f32_16x16x32_bf16((a), (b), (c), 0, 0, 0)

// async global->LDS, 16B per lane; lds ptr must be wave-uniform
#define GLD16(lptr, gptr) __builtin_amdgcn_global_load_lds( \
    (__attribute__((address_space(1))) void*)(gptr), \
    (__attribute__((address_space(3))) void*)(lptr), 16, 0, 0)

// ---- bf16 split helpers (RNE via bit trick; no NaN inputs here) ----
__device__ inline us f2bf(float f) {
  u32 u = __float_as_uint(f);
  u32 r = (u + 0x7FFFu + ((u >> 16) & 1u)) >> 16;
  return (us)r;
}
__device__ inline float bf2f(us s) { return __uint_as_float((u32)s << 16); }
__device__ inline void splitbf(float x, us& hi, us& lo) {
  hi = f2bf(x);
  lo = f2bf(x - bf2f(hi));
}

// ================= init small accumulators =================
__global__ void k_init(float* accs, int* cnt, int* cursor) {
  int t = threadIdx.x;
  if (t < 68) accs[t] = 0.f;
  if (t < 65) { cnt[t] = 0; cursor[t] = 0; }
}

// ================= dropout mask: JAX threefry2x32, key (0,42) =================
#define TF_R(a) { x0 += x1; x1 = (x1 << (a)) | (x1 >> (32 - (a))); x1 ^= x0; }
__global__ void k_mask(u32* __restrict__ mask) {
  u32 t = blockIdx.x * 256u + threadIdx.x;  // 0..131071
  const u32 K0 = 0u, K1 = 42u, K2 = 0x1BD11BDAu ^ 0u ^ 42u;
  u32 w0 = 0, w1 = 0;
  for (int i = 0; i < 32; ++i) {
    u32 x0 = t * 32u + (u32)i;
    u32 x1 = x0 + 4194304u;
    x0 += K0; x1 += K1;
    TF_R(13) TF_R(15) TF_R(26) TF_R(6)   x0 += K1; x1 += K2 + 1u;
    TF_R(17) TF_R(29) TF_R(16) TF_R(24)  x0 += K2; x1 += K0 + 2u;
    TF_R(13) TF_R(15) TF_R(26) TF_R(6)   x0 += K0; x1 += K1 + 3u;
    TF_R(17) TF_R(29) TF_R(16) TF_R(24)  x0 += K1; x1 += K2 + 4u;
    TF_R(13) TF_R(15) TF_R(26) TF_R(6)   x0 += K2; x1 += K0 + 5u;
    w0 |= (u32)((x0 >> 31) == 0u) << i;  // uniform<0.5  <=>  top bit 0
    w1 |= (u32)((x1 >> 31) == 0u) << i;
  }
  mask[t] = w0;
  mask[t + 131072u] = w1;
}

// ================= split+transpose w1 [2048][512] -> w1t planes [512][2048] =================
__global__ void k_splitw1(const float* __restrict__ w1, us* __restrict__ th, us* __restrict__ tl) {
  __shared__ float tile[64][65];
  int k0 = blockIdx.x * 64, n0 = blockIdx.y * 64;
  int t = threadIdx.x;
  int cr = t >> 6, cc = t & 63;
  for (int i = 0; i < 16; ++i) {
    int r = i * 4 + cr;
    tile[r][cc] = w1[(size_t)(k0 + r) * 512 + n0 + cc];
  }
  __syncthreads();
  for (int i = 0; i < 16; ++i) {
    int n = i * 4 + cr;
    int k = cc;
    us hi, lo; splitbf(tile[k][n], hi, lo);
    size_t o = (size_t)(n0 + n) * 2048 + k0 + k;
    th[o] = hi; tl[o] = lo;
  }
}

// ================= split+transpose w2 [512][65] -> w2t planes [80][512] (pad zero) =================
__global__ void k_splitw2(const float* __restrict__ w2, us* __restrict__ th, us* __restrict__ tl) {
  int n = blockIdx.x;  // 0..79
  for (int k = threadIdx.x; k < 512; k += 256) {
    float v = (n < 65) ? w2[(size_t)k * 65 + n] : 0.f;
    us hi, lo; splitbf(v, hi, lo);
    th[n * 512 + k] = hi; tl[n * 512 + k] = lo;
  }
}

// ================= split feat fp32 -> hi/lo bf16 planes =================
__global__ void k_splitfeat(const float* __restrict__ x, us* __restrict__ xh, us* __restrict__ xl) {
  size_t g = ((size_t)blockIdx.x * 256 + threadIdx.x) * 8;
  f32x4 a = *(const f32x4*)(x + g);
  f32x4 b = *(const f32x4*)(x + g + 4);
  short8 h8, l8;
  for (int i = 0; i < 4; ++i) {
    us hi, lo;
    splitbf(a[i], hi, lo); h8[i] = (short)hi; l8[i] = (short)lo;
    splitbf(b[i], hi, lo); h8[4 + i] = (short)hi; l8[4 + i] = (short)lo;
  }
  *(short8*)(xh + g) = h8;
  *(short8*)(xl + g) = l8;
}

// ================= GEMM1: h = dropout(relu(feat@w1 + b1)), bf16x3, 128x128x32 =================
__global__ __launch_bounds__(256, 2) void k_gemm1(
    const us* __restrict__ Ah_, const us* __restrict__ Al_,   // feat planes [16384][2048]
    const us* __restrict__ Bh_, const us* __restrict__ Bl_,   // w1t planes  [512][2048]
    const float* __restrict__ b1, const u32* __restrict__ mask,
    us* __restrict__ Hh, us* __restrict__ Hl) {
  __shared__ __align__(16) us lds[4 * 4096];  // Ah, Al, Bh, Bl tiles [128][32]
  us* sAh = lds; us* sAl = lds + 4096; us* sBh = lds + 8192; us* sBl = lds + 12288;
  int tid = threadIdx.x;
  int bn = blockIdx.x, bm = blockIdx.y;
  int m0 = bm * 128, n0 = bn * 128;
  int lane = tid & 63, wv = tid >> 6;
  int wm = (wv >> 1) * 64, wn = (wv & 1) * 64;
  int frow = lane & 15, fk = (lane >> 4) * 8;
  int srow = tid >> 2, scol = (tid & 3) * 8;
  f32x4 acc[4][4] = {};
  size_t arow = (size_t)(m0 + srow) * 2048 + scol;
  size_t brow = (size_t)(n0 + srow) * 2048 + scol;
  for (int kt = 0; kt < 64; ++kt) {
    int k0 = kt * 32;
    __syncthreads();
    GLD16(sAh + wv * 512,        Ah_ + arow + k0);
    GLD16(sAh + 2048 + wv * 512, Ah_ + arow + (size_t)64 * 2048 + k0);
    GLD16(sAl + wv * 512,        Al_ + arow + k0);
    GLD16(sAl + 2048 + wv * 512, Al_ + arow + (size_t)64 * 2048 + k0);
    GLD16(sBh + wv * 512,        Bh_ + brow + k0);
    GLD16(sBh + 2048 + wv * 512, Bh_ + brow + (size_t)64 * 2048 + k0);
    GLD16(sBl + wv * 512,        Bl_ + brow + k0);
    GLD16(sBl + 2048 + wv * 512, Bl_ + brow + (size_t)64 * 2048 + k0);
    __syncthreads();
    short8 ah[4], al[4], bh[4], bl[4];
#pragma unroll
    for (int f = 0; f < 4; ++f) {
      ah[f] = *(const short8*)&sAh[(wm + f * 16 + frow) * 32 + fk];
      al[f] = *(const short8*)&sAl[(wm + f * 16 + frow) * 32 + fk];
      bh[f] = *(const short8*)&sBh[(wn + f * 16 + frow) * 32 + fk];
      bl[f] = *(const short8*)&sBl[(wn + f * 16 + frow) * 32 + fk];
    }
#pragma unroll
    for (int i = 0; i < 4; ++i)
#pragma unroll
      for (int j = 0; j < 4; ++j) {
        acc[i][j] = MFMA16(ah[i], bh[j], acc[i][j]);
        acc[i][j] = MFMA16(ah[i], bl[j], acc[i][j]);
        acc[i][j] = MFMA16(al[i], bh[j], acc[i][j]);
      }
  }
  // epilogue: +b1, relu, dropout, split to bf16 hi/lo
#pragma unroll
  for (int i = 0; i < 4; ++i)
#pragma unroll
    for (int j = 0; j < 4; ++j)
#pragma unroll
      for (int r = 0; r < 4; ++r) {
        int row = m0 + wm + i * 16 + (lane >> 4) * 4 + r;
        int col = n0 + wn + j * 16 + (lane & 15);
        float v = acc[i][j][r] + b1[col];
        v = fmaxf(v, 0.f);
        u32 f = (u32)row * 512u + (u32)col;
        u32 keep = (mask[f >> 5] >> (f & 31u)) & 1u;
        v = keep ? v * 2.f : 0.f;
        us hi, lo; splitbf(v, hi, lo);
        size_t o = (size_t)row * 512 + col;
        Hh[o] = hi; Hl[o] = lo;
      }
}

// ================= GEMM2 (64x80, K=512) + fused softmax stats =================
__global__ __launch_bounds__(256, 2) void k_gemm2(
    const us* __restrict__ Ah_, const us* __restrict__ Al_,   // h planes [16384][512]
    const us* __restrict__ Bh_, const us* __restrict__ Bl_,   // w2t planes [80][512]
    const float* __restrict__ b2,
    float* __restrict__ logp, int* __restrict__ preds,
    float* __restrict__ accs /* [0] ent, [2..] mp */) {
  __shared__ __align__(16) us sA[2][2048];   // [64][32] hi/lo
  __shared__ __align__(16) us sB[2][2560];   // [80][32] hi/lo
  __shared__ float slog[64 * 81];
  __shared__ float sm[64], sl[64];
  __shared__ float sred[256];
  int tid = threadIdx.x;
  int m0 = blockIdx.x * 64;
  int lane = tid & 63, wv = tid >> 6;
  int frow = lane & 15, fk = (lane >> 4) * 8;
  int srow = tid >> 2, scol = (tid & 3) * 8;
  int r2 = 64 + (lane >> 2), sc2 = (lane & 3) * 8;
  f32x4 acc[5] = {};
  size_t arow = (size_t)(m0 + srow) * 512 + scol;
  size_t brow = (size_t)srow * 512 + scol;
  size_t brow2 = (size_t)r2 * 512 + sc2;
  for (int kt = 0; kt < 16; ++kt) {
    int k0 = kt * 32;
    __syncthreads();
    GLD16(&sA[0][wv * 512], Ah_ + arow + k0);
    GLD16(&sA[1][wv * 512], Al_ + arow + k0);
    GLD16(&sB[0][wv * 512], Bh_ + brow + k0);
    GLD16(&sB[1][wv * 512], Bl_ + brow + k0);
    if (wv == 0) {
      GLD16(&sB[0][2048], Bh_ + brow2 + k0);
      GLD16(&sB[1][2048], Bl_ + brow2 + k0);
    }
    __syncthreads();
    short8 a_h = *(const short8*)&sA[0][(wv * 16 + frow) * 32 + fk];
    short8 a_l = *(const short8*)&sA[1][(wv * 16 + frow) * 32 + fk];
#pragma unroll
    for (int fn = 0; fn < 5; ++fn) {
      short8 b_h = *(const short8*)&sB[0][(fn * 16 + frow) * 32 + fk];
      short8 b_l = *(const short8*)&sB[1][(fn * 16 + frow) * 32 + fk];
      acc[fn] = MFMA16(a_h, b_h, acc[fn]);
      acc[fn] = MFMA16(a_h, b_l, acc[fn]);
      acc[fn] = MFMA16(a_l, b_h, acc[fn]);
    }
  }
  // logits -> LDS (+bias)
#pragma unroll
  for (int fn = 0; fn < 5; ++fn) {
    int col = fn * 16 + (lane & 15);
    if (col < 65) {
      float bb = b2[col];
#pragma unroll
      for (int r = 0; r < 4; ++r) {
        int row = wv * 16 + (lane >> 4) * 4 + r;
        slog[row * 81 + col] = acc[fn][r] + bb;
      }
    }
  }
  __syncthreads();
  if (tid < 64) {
    int row = tid;
    float m = -1e30f; int am = 0;
    for (int c = 0; c < 65; ++c) {
      float v = slog[row * 81 + c];
      if (v > m) { m = v; am = c; }   // first-max: strict >
    }
    float s = 0.f;
    for (int c = 0; c < 65; ++c) s += expf(slog[row * 81 + c] - m);
    sm[row] = m; sl[row] = logf(s);
    preds[m0 + row] = am;
  }
  __syncthreads();
  float entp = 0.f;
  if (tid < 240) {
    int c = tid % 80, rr0 = tid / 80;
    if (c < 65) {
      float mpp = 0.f;
      for (int r = rr0; r < 64; r += 3) {
        float v = slog[r * 81 + c] - sm[r] - sl[r];
        logp[(size_t)(m0 + r) * 65 + c] = v;
        float p = expf(v);
        mpp += p;
        entp += p * logf(p + 1e-6f);
      }
      atomicAdd(&accs[2 + c], mpp);
    }
  }
  sred[tid] = entp;
  __syncthreads();
  for (int s = 128; s > 0; s >>= 1) { if (tid < s) sred[tid] += sred[tid + s]; __syncthreads(); }
  if (tid == 0) atomicAdd(&accs[0], sred[0]);
}

// ================= histogram of preds =================
__global__ __launch_bounds__(256) void k_hist(const int* __restrict__ preds, int* __restrict__ cnt) {
  __shared__ int h[65];
  int tid = threadIdx.x;
  if (tid < 65) h[tid] = 0;
  __syncthreads();
  int i = blockIdx.x * 256 + tid;
  atomicAdd(&h[preds[i]], 1);
  __syncthreads();
  if (tid < 65 && h[tid] > 0) atomicAdd(&cnt[tid], h[tid]);
}

// ================= exclusive prefix -> base =================
__global__ void k_scan(const int* __restrict__ cnt, int* __restrict__ base) {
  if (threadIdx.x == 0) {
    int s = 0;
    for (int c = 0; c < 65; ++c) { base[c] = s; s += cnt[c]; }
  }
}

// ================= scatter row indices grouped by class =================
__global__ __launch_bounds__(256) void k_scatter(
    const int* __restrict__ preds, const int* __restrict__ base,
    int* __restrict__ cursor, int* __restrict__ rowidx) {
  __shared__ int h[65];      // per-block per-class count
  __shared__ int gb[65];     // per-block reserved global offset
  int tid = threadIdx.x;
  if (tid < 65) h[tid] = 0;
  __syncthreads();
  int i = blockIdx.x * 256 + tid;
  int c = preds[i];
  int pos = atomicAdd(&h[c], 1);     // rank within block for this class
  __syncthreads();
  if (tid < 65 && h[tid] > 0) gb[tid] = atomicAdd(&cursor[tid], h[tid]);
  __syncthreads();
  rowidx[base[c] + gb[c] + pos] = i;
}

// ================= segment sums: gather rows per class, register accumulate =================
__global__ __launch_bounds__(256) void k_segsum2(
    const float* __restrict__ feat, const int* __restrict__ rowidx,
    const int* __restrict__ base, const int* __restrict__ cnt,
    float* __restrict__ psum /* [8][65][2048] */) {
  int c = blockIdx.x;   // 0..64
  int j = blockIdx.y;   // 0..7
  int tid = threadIdx.x;
  int start = base[c], n = cnt[c];
  f32x4 a0 = {}, a1 = {};
  const float* fp = feat + (size_t)tid * 8;
  for (int i = j; i < n; i += 8) {
    int row = rowidx[start + i];
    const f32x4* p = (const f32x4*)(fp + (size_t)row * 2048);
    a0 += p[0];
    a1 += p[1];
  }
  float* o = psum + ((size_t)(j * 65 + c)) * 2048 + (size_t)tid * 8;
  *(f32x4*)o = a0;
  *(f32x4*)(o + 4) = a1;
}

// ================= centroids: reduce partials, normalize, split bf16; B^T layout [80][2048] =================
__global__ __launch_bounds__(256) void k_centroid(
    const float* __restrict__ psum, const int* __restrict__ pcnt,
    us* __restrict__ ch, us* __restrict__ cl) {
  int c = blockIdx.x;  // 0..79
  int tid = threadIdx.x;
  if (c >= 65) {
    for (int d = tid; d < 2048; d += 256) { ch[(size_t)c * 2048 + d] = 0; cl[(size_t)c * 2048 + d] = 0; }
    return;
  }
  int cnt = pcnt[c];
  float inv = 1.0f / (float)((cnt > 1) ? cnt : 1);
  float mean[8]; float sq = 0.f;
  for (int i = 0; i < 8; ++i) {
    int d = tid + i * 256;
    float s = 0.f;
    for (int nc = 0; nc < 8; ++nc) s += psum[((size_t)nc * 65 + c) * 2048 + d];
    mean[i] = s * inv;
    sq += mean[i] * mean[i];
  }
  __shared__ float red[256];
  red[tid] = sq; __syncthreads();
  for (int s = 128; s > 0; s >>= 1) { if (tid < s) red[tid] += red[tid + s]; __syncthreads(); }
  float norm = sqrtf(red[0]);
  float dscale = (cnt > 0) ? 1.0f / fmaxf(norm, 1e-12f) : 0.0f;
  for (int i = 0; i < 8; ++i) {
    int d = tid + i * 256;
    us hi, lo; splitbf(mean[i] * dscale, hi, lo);
    ch[(size_t)c * 2048 + d] = hi; cl[(size_t)c * 2048 + d] = lo;
  }
}

// ================= sim GEMM (64x80, K=2048) + argmax + CE gather =================
__global__ __launch_bounds__(256, 2) void k_sim(
    const us* __restrict__ Ah_, const us* __restrict__ Al_,   // feat planes [16384][2048]
    const us* __restrict__ Bh_, const us* __restrict__ Bl_,   // cent planes [80][2048]
    const float* __restrict__ logp, float* __restrict__ accs /* [1]=ce */) {
  __shared__ __align__(16) us sA[2][2048];
  __shared__ __align__(16) us sB[2][2560];
  __shared__ float ssim[64 * 81];
  __shared__ float sred[256];
  int tid = threadIdx.x;
  int m0 = blockIdx.x * 64;
  int lane = tid & 63, wv = tid >> 6;
  int frow = lane & 15, fk = (lane >> 4) * 8;
  int srow = tid >> 2, scol = (tid & 3) * 8;
  int r2 = 64 + (lane >> 2), sc2 = (lane & 3) * 8;
  f32x4 acc[5] = {};
  size_t arow = (size_t)(m0 + srow) * 2048 + scol;
  size_t brow = (size_t)srow * 2048 + scol;
  size_t brow2 = (size_t)r2 * 2048 + sc2;
  for (int kt = 0; kt < 64; ++kt) {
    int k0 = kt * 32;
    __syncthreads();
    GLD16(&sA[0][wv * 512], Ah_ + arow + k0);
    GLD16(&sA[1][wv * 512], Al_ + arow + k0);
    GLD16(&sB[0][wv * 512], Bh_ + brow + k0);
    GLD16(&sB[1][wv * 512], Bl_ + brow + k0);
    if (wv == 0) {
      GLD16(&sB[0][2048], Bh_ + brow2 + k0);
      GLD16(&sB[1][2048], Bl_ + brow2 + k0);
    }
    __syncthreads();
    short8 a_h = *(const short8*)&sA[0][(wv * 16 + frow) * 32 + fk];
    short8 a_l = *(const short8*)&sA[1][(wv * 16 + frow) * 32 + fk];
#pragma unroll
    for (int fn = 0; fn < 5; ++fn) {
      short8 b_h = *(const short8*)&sB[0][(fn * 16 + frow) * 32 + fk];
      short8 b_l = *(const short8*)&sB[1][(fn * 16 + frow) * 32 + fk];
      acc[fn] = MFMA16(a_h, b_h, acc[fn]);
      acc[fn] = MFMA16(a_h, b_l, acc[fn]);
      acc[fn] = MFMA16(a_l, b_h, acc[fn]);
    }
  }
#pragma unroll
  for (int fn = 0; fn < 5; ++fn) {
    int col = fn * 16 + (lane & 15);
    if (col < 65)
#pragma unroll
      for (int r = 0; r < 4; ++r)
        ssim[(wv * 16 + (lane >> 4) * 4 + r) * 81 + col] = acc[fn][r];
  }
  __syncthreads();
  float cep = 0.f;
  if (tid < 64) {
    float m = -1e30f; int am = 0;
    for (int c = 0; c < 65; ++c) {
      float v = ssim[tid * 81 + c];
      if (v > m) { m = v; am = c; }
    }
    cep = logp[(size_t)(m0 + tid) * 65 + am];
  }
  sred[tid] = cep;
  __syncthreads();
  for (int s = 128; s > 0; s >>= 1) { if (tid < s) sred[tid] += sred[tid + s]; __syncthreads(); }
  if (tid == 0) atomicAdd(&accs[1], sred[0]);
}

// ================= final combine =================
__global__ void k_final(const float* __restrict__ accs, float* __restrict__ out) {
  __shared__ float red[256];
  int t = threadIdx.x;
  float d = 0.f;
  if (t < 65) {
    float mp = accs[2 + t] * (1.f / 16384.f);
    d = mp * logf(mp + 1e-6f);
  }
  red[t] = d; __syncthreads();
  for (int s = 128; s > 0; s >>= 1) { if (t < s) red[t] += red[t + s]; __syncthreads(); }
  if (t == 0) {
    float entropy = -accs[0] * (1.f / 16384.f);
    float ce = -accs[1] * (1.f / 16384.f);
    out[0] = entropy + red[0] + 0.3f * ce;
  }
}

extern "C" void kernel_launch(void* const* d_in, const int* in_sizes, int n_in,
                              void* d_out, int out_size, void* d_ws, size_t ws_size,
                              hipStream_t stream) {
  const float* feat = (const float*)d_in[0];
  const float* w1   = (const float*)d_in[1];
  const float* b1   = (const float*)d_in[2];
  const float* w2   = (const float*)d_in[3];
  const float* b2   = (const float*)d_in[4];
  float* out = (float*)d_out;

  char* w = (char*)d_ws;
  auto alloc = [&](size_t b) { char* p = w; w += (b + 255) & ~(size_t)255; return p; };
  us*  feat_hi = (us*)alloc(16384ull * 2048 * 2);
  us*  feat_lo = (us*)alloc(16384ull * 2048 * 2);
  us*  w1t_hi  = (us*)alloc(512ull * 2048 * 2);
  us*  w1t_lo  = (us*)alloc(512ull * 2048 * 2);
  us*  w2t_hi  = (us*)alloc(80ull * 512 * 2);
  us*  w2t_lo  = (us*)alloc(80ull * 512 * 2);
  u32* mask    = (u32*)alloc(262144ull * 4);
  us*  h_hi    = (us*)alloc(16384ull * 512 * 2);
  us*  h_lo    = (us*)alloc(16384ull * 512 * 2);
  float* logp  = (float*)alloc(16384ull * 65 * 4);
  int*   preds = (int*)alloc(16384ull * 4);
  float* psum  = (float*)alloc(8ull * 65 * 2048 * 4);
  int*   cnt   = (int*)alloc(65ull * 4);
  int*   base  = (int*)alloc(65ull * 4);
  int*   cursor= (int*)alloc(65ull * 4);
  int*   rowidx= (int*)alloc(16384ull * 4);
  us*  cent_hi = (us*)alloc(80ull * 2048 * 2);
  us*  cent_lo = (us*)alloc(80ull * 2048 * 2);
  float* accs  = (float*)alloc(68ull * 4);

  k_init<<<1, 256, 0, stream>>>(accs, cnt, cursor);
  k_mask<<<512, 256, 0, stream>>>(mask);
  k_splitw1<<<dim3(32, 8), 256, 0, stream>>>(w1, w1t_hi, w1t_lo);
  k_splitw2<<<80, 256, 0, stream>>>(w2, w2t_hi, w2t_lo);
  k_splitfeat<<<16384, 256, 0, stream>>>(feat, feat_hi, feat_lo);
  k_gemm1<<<dim3(4, 128), 256, 0, stream>>>(feat_hi, feat_lo, w1t_hi, w1t_lo, b1, mask, h_hi, h_lo);
  k_gemm2<<<256, 256, 0, stream>>>(h_hi, h_lo, w2t_hi, w2t_lo, b2, logp, preds, accs);
  k_hist<<<64, 256, 0, stream>>>(preds, cnt);
  k_scan<<<1, 64, 0, stream>>>(cnt, base);
  k_scatter<<<64, 256, 0, stream>>>(preds, base, cursor, rowidx);
  k_segsum2<<<dim3(65, 8), 256, 0, stream>>>(feat, rowidx, base, cnt, psum);
  k_centroid<<<80, 256, 0, stream>>>(psum, cnt, cent_hi, cent_lo);
  k_sim<<<256, 256, 0, stream>>>(feat_hi, feat_lo, cent_hi, cent_lo, logp, accs);
  k_final<<<1, 256, 0, stream>>>(accs, out);
}

// Round 3
// 534.580 us; speedup vs baseline: 1.2166x; 1.0482x over previous
//
#include <hip/hip_runtime.h>

typedef unsigned short us;
typedef unsigned int u32;
typedef __attribute__((ext_vector_type(8))) short short8;
typedef __attribute__((ext_vector_type(4))) float f32x4;

#define MFMA16(a, b, c) __builtin_amdgcn_mfma_f32_16x16x32_bf16((a), (b), (c), 0, 0, 0)

// async global->LDS, 16B per lane; lds ptr must be wave-uniform
#define GLD16(lptr, gptr) __builtin_amdgcn_global_load_lds( \
    (__attribute__((address_space(1))) void*)(gptr), \
    (__attribute__((address_space(3))) void*)(lptr), 16, 0, 0)

// ---- bf16 split helpers (RNE via bit trick; no NaN inputs here) ----
__device__ inline us f2bf(float f) {
  u32 u = __float_as_uint(f);
  u32 r = (u + 0x7FFFu + ((u >> 16) & 1u)) >> 16;
  return (us)r;
}
__device__ inline float bf2f(us s) { return __uint_as_float((u32)s << 16); }
__device__ inline void splitbf(float x, us& hi, us& lo) {
  hi = f2bf(x);
  lo = f2bf(x - bf2f(hi));
}

// ================= init small accumulators =================
__global__ void k_init(float* accs, int* cnt, int* cursor) {
  int t = threadIdx.x;
  if (t < 68) accs[t] = 0.f;
  if (t < 65) { cnt[t] = 0; cursor[t] = 0; }
}

// ================= dropout mask: JAX threefry2x32, key (0,42) =================
#define TF_R(a) { x0 += x1; x1 = (x1 << (a)) | (x1 >> (32 - (a))); x1 ^= x0; }
__global__ void k_mask(u32* __restrict__ mask) {
  u32 t = blockIdx.x * 256u + threadIdx.x;  // 0..131071
  const u32 K0 = 0u, K1 = 42u, K2 = 0x1BD11BDAu ^ 0u ^ 42u;
  u32 w0 = 0, w1 = 0;
  for (int i = 0; i < 32; ++i) {
    u32 x0 = t * 32u + (u32)i;
    u32 x1 = x0 + 4194304u;
    x0 += K0; x1 += K1;
    TF_R(13) TF_R(15) TF_R(26) TF_R(6)   x0 += K1; x1 += K2 + 1u;
    TF_R(17) TF_R(29) TF_R(16) TF_R(24)  x0 += K2; x1 += K0 + 2u;
    TF_R(13) TF_R(15) TF_R(26) TF_R(6)   x0 += K0; x1 += K1 + 3u;
    TF_R(17) TF_R(29) TF_R(16) TF_R(24)  x0 += K1; x1 += K2 + 4u;
    TF_R(13) TF_R(15) TF_R(26) TF_R(6)   x0 += K2; x1 += K0 + 5u;
    w0 |= (u32)((x0 >> 31) == 0u) << i;  // uniform<0.5  <=>  top bit 0
    w1 |= (u32)((x1 >> 31) == 0u) << i;
  }
  mask[t] = w0;
  mask[t + 131072u] = w1;
}

// ================= split+transpose w1 [2048][512] -> w1t planes [512][2048] =================
__global__ void k_splitw1(const float* __restrict__ w1, us* __restrict__ th, us* __restrict__ tl) {
  __shared__ float tile[64][65];
  int k0 = blockIdx.x * 64, n0 = blockIdx.y * 64;
  int t = threadIdx.x;
  int cr = t >> 6, cc = t & 63;
  for (int i = 0; i < 16; ++i) {
    int r = i * 4 + cr;
    tile[r][cc] = w1[(size_t)(k0 + r) * 512 + n0 + cc];
  }
  __syncthreads();
  for (int i = 0; i < 16; ++i) {
    int n = i * 4 + cr;
    int k = cc;
    us hi, lo; splitbf(tile[k][n], hi, lo);
    size_t o = (size_t)(n0 + n) * 2048 + k0 + k;
    th[o] = hi; tl[o] = lo;
  }
}

// ================= split+transpose w2 [512][65] -> w2t planes [80][512] (pad zero) =================
__global__ void k_splitw2(const float* __restrict__ w2, us* __restrict__ th, us* __restrict__ tl) {
  int n = blockIdx.x;  // 0..79
  for (int k = threadIdx.x; k < 512; k += 256) {
    float v = (n < 65) ? w2[(size_t)k * 65 + n] : 0.f;
    us hi, lo; splitbf(v, hi, lo);
    th[n * 512 + k] = hi; tl[n * 512 + k] = lo;
  }
}

// ================= split feat fp32 -> hi/lo bf16 planes =================
__global__ void k_splitfeat(const float* __restrict__ x, us* __restrict__ xh, us* __restrict__ xl) {
  size_t g = ((size_t)blockIdx.x * 256 + threadIdx.x) * 8;
  f32x4 a = *(const f32x4*)(x + g);
  f32x4 b = *(const f32x4*)(x + g + 4);
  short8 h8, l8;
  for (int i = 0; i < 4; ++i) {
    us hi, lo;
    splitbf(a[i], hi, lo); h8[i] = (short)hi; l8[i] = (short)lo;
    splitbf(b[i], hi, lo); h8[4 + i] = (short)hi; l8[4 + i] = (short)lo;
  }
  *(short8*)(xh + g) = h8;
  *(short8*)(xl + g) = l8;
}

// ================= GEMM1: h = dropout(relu(feat@w1 + b1)), bf16x3, 128x128x64 =================
// grid dim3(128,4): bm = blockIdx.x so the 4 N-blocks sharing an A panel land on the same XCD.
// LDS layout [row][64] with k-chunk XOR swizzle (chunk ^ row&7) -> 2-way banks (free).
__global__ __launch_bounds__(256, 2) void k_gemm1(
    const us* __restrict__ Ah_, const us* __restrict__ Al_,   // feat planes [16384][2048]
    const us* __restrict__ Bh_, const us* __restrict__ Bl_,   // w1t planes  [512][2048]
    const float* __restrict__ b1, const u32* __restrict__ mask,
    us* __restrict__ Hh, us* __restrict__ Hl) {
  __shared__ __align__(16) us lds[4 * 8192];  // Ah, Al, Bh, Bl tiles [128][64]
  us* sAh = lds; us* sAl = lds + 8192; us* sBh = lds + 16384; us* sBl = lds + 24576;
  int tid = threadIdx.x;
  int bm = blockIdx.x, bn = blockIdx.y;
  int m0 = bm * 128, n0 = bn * 128;
  int lane = tid & 63, wv = tid >> 6;
  int wm = (wv >> 1) * 64, wn = (wv & 1) * 64;
  int frow = lane & 15, fq = lane >> 4;      // fq: 16B k-chunk within 32-us half
  int srow = tid >> 3;                        // 0..31 (rows per staging call)
  int scolsw = (((tid & 7) ^ ((tid >> 3) & 7)) * 8);  // swizzled source chunk
  f32x4 acc[4][4] = {};
  size_t arow = (size_t)(m0 + srow) * 2048 + scolsw;
  size_t brow = (size_t)(n0 + srow) * 2048 + scolsw;
  for (int kt = 0; kt < 32; ++kt) {
    int k0 = kt * 64;
    __syncthreads();
#pragma unroll
    for (int j = 0; j < 4; ++j) {
      int lo = j * 2048 + wv * 512;
      size_t go = (size_t)j * 32 * 2048 + k0;
      GLD16(sAh + lo, Ah_ + arow + go);
      GLD16(sAl + lo, Al_ + arow + go);
      GLD16(sBh + lo, Bh_ + brow + go);
      GLD16(sBl + lo, Bl_ + brow + go);
    }
    __syncthreads();
#pragma unroll
    for (int s = 0; s < 2; ++s) {
      short8 ah[4], al[4], bh[4], bl[4];
#pragma unroll
      for (int f = 0; f < 4; ++f) {
        int ca = ((s * 4 + fq) ^ (frow & 7)) * 8;
        int ra = (wm + f * 16 + frow) * 64 + ca;
        int rb = (wn + f * 16 + frow) * 64 + ca;
        ah[f] = *(const short8*)&sAh[ra];
        al[f] = *(const short8*)&sAl[ra];
        bh[f] = *(const short8*)&sBh[rb];
        bl[f] = *(const short8*)&sBl[rb];
      }
#pragma unroll
      for (int i = 0; i < 4; ++i)
#pragma unroll
        for (int j2 = 0; j2 < 4; ++j2) {
          acc[i][j2] = MFMA16(ah[i], bh[j2], acc[i][j2]);
          acc[i][j2] = MFMA16(ah[i], bl[j2], acc[i][j2]);
          acc[i][j2] = MFMA16(al[i], bh[j2], acc[i][j2]);
        }
    }
  }
  // epilogue: +b1, relu, dropout, split to bf16 hi/lo
#pragma unroll
  for (int i = 0; i < 4; ++i)
#pragma unroll
    for (int j = 0; j < 4; ++j)
#pragma unroll
      for (int r = 0; r < 4; ++r) {
        int row = m0 + wm + i * 16 + (lane >> 4) * 4 + r;
        int col = n0 + wn + j * 16 + (lane & 15);
        float v = acc[i][j][r] + b1[col];
        v = fmaxf(v, 0.f);
        u32 f = (u32)row * 512u + (u32)col;
        u32 keep = (mask[f >> 5] >> (f & 31u)) & 1u;
        v = keep ? v * 2.f : 0.f;
        us hi, lo; splitbf(v, hi, lo);
        size_t o = (size_t)row * 512 + col;
        Hh[o] = hi; Hl[o] = lo;
      }
}

// ================= GEMM2 (64x80, K=512, BK=64) + fused softmax stats =================
__global__ __launch_bounds__(256, 2) void k_gemm2(
    const us* __restrict__ Ah_, const us* __restrict__ Al_,   // h planes [16384][512]
    const us* __restrict__ Bh_, const us* __restrict__ Bl_,   // w2t planes [80][512]
    const float* __restrict__ b2,
    float* __restrict__ logp, int* __restrict__ preds,
    float* __restrict__ accs /* [0] ent, [2..] mp */) {
  __shared__ __align__(16) us sA[2][4096];   // [64][64] hi/lo
  __shared__ __align__(16) us sB[2][5120];   // [80][64] hi/lo
  __shared__ float slog[64 * 81];
  __shared__ float sm[64], sl[64];
  __shared__ float sred[256];
  int tid = threadIdx.x;
  int m0 = blockIdx.x * 64;
  int lane = tid & 63, wv = tid >> 6;
  int frow = lane & 15, fq = lane >> 4;
  int srow = tid >> 3;
  int scolsw = (((tid & 7) ^ ((tid >> 3) & 7)) * 8);
  f32x4 acc[5] = {};
  size_t arow = (size_t)(m0 + srow) * 512 + scolsw;
  size_t brow = (size_t)srow * 512 + scolsw;
  size_t brow2 = (size_t)(64 + (tid >> 3)) * 512 + scolsw;  // rows 64..79 (tid<128)
  for (int kt = 0; kt < 8; ++kt) {
    int k0 = kt * 64;
    __syncthreads();
#pragma unroll
    for (int j = 0; j < 2; ++j) {
      int lo = j * 2048 + wv * 512;
      size_t go = (size_t)j * 32 * 512 + k0;
      GLD16(&sA[0][lo], Ah_ + arow + go);
      GLD16(&sA[1][lo], Al_ + arow + go);
      GLD16(&sB[0][lo], Bh_ + brow + go);
      GLD16(&sB[1][lo], Bl_ + brow + go);
    }
    if (wv < 2) {
      GLD16(&sB[0][4096 + wv * 512], Bh_ + brow2 + k0);
      GLD16(&sB[1][4096 + wv * 512], Bl_ + brow2 + k0);
    }
    __syncthreads();
#pragma unroll
    for (int s = 0; s < 2; ++s) {
      int ca = ((s * 4 + fq) ^ (frow & 7)) * 8;
      short8 a_h = *(const short8*)&sA[0][(wv * 16 + frow) * 64 + ca];
      short8 a_l = *(const short8*)&sA[1][(wv * 16 + frow) * 64 + ca];
#pragma unroll
      for (int fn = 0; fn < 5; ++fn) {
        short8 b_h = *(const short8*)&sB[0][(fn * 16 + frow) * 64 + ca];
        short8 b_l = *(const short8*)&sB[1][(fn * 16 + frow) * 64 + ca];
        acc[fn] = MFMA16(a_h, b_h, acc[fn]);
        acc[fn] = MFMA16(a_h, b_l, acc[fn]);
        acc[fn] = MFMA16(a_l, b_h, acc[fn]);
      }
    }
  }
  // logits -> LDS (+bias)
#pragma unroll
  for (int fn = 0; fn < 5; ++fn) {
    int col = fn * 16 + (lane & 15);
    if (col < 65) {
      float bb = b2[col];
#pragma unroll
      for (int r = 0; r < 4; ++r) {
        int row = wv * 16 + (lane >> 4) * 4 + r;
        slog[row * 81 + col] = acc[fn][r] + bb;
      }
    }
  }
  __syncthreads();
  if (tid < 64) {
    int row = tid;
    float m = -1e30f; int am = 0;
    for (int c = 0; c < 65; ++c) {
      float v = slog[row * 81 + c];
      if (v > m) { m = v; am = c; }   // first-max: strict >
    }
    float s = 0.f;
    for (int c = 0; c < 65; ++c) s += expf(slog[row * 81 + c] - m);
    sm[row] = m; sl[row] = logf(s);
    preds[m0 + row] = am;
  }
  __syncthreads();
  float entp = 0.f;
  if (tid < 240) {
    int c = tid % 80, rr0 = tid / 80;
    if (c < 65) {
      float mpp = 0.f;
      for (int r = rr0; r < 64; r += 3) {
        float v = slog[r * 81 + c] - sm[r] - sl[r];
        logp[(size_t)(m0 + r) * 65 + c] = v;
        float p = expf(v);
        mpp += p;
        entp += p * logf(p + 1e-6f);
      }
      atomicAdd(&accs[2 + c], mpp);
    }
  }
  sred[tid] = entp;
  __syncthreads();
  for (int s = 128; s > 0; s >>= 1) { if (tid < s) sred[tid] += sred[tid + s]; __syncthreads(); }
  if (tid == 0) atomicAdd(&accs[0], sred[0]);
}

// ================= histogram of preds =================
__global__ __launch_bounds__(256) void k_hist(const int* __restrict__ preds, int* __restrict__ cnt) {
  __shared__ int h[65];
  int tid = threadIdx.x;
  if (tid < 65) h[tid] = 0;
  __syncthreads();
  int i = blockIdx.x * 256 + tid;
  atomicAdd(&h[preds[i]], 1);
  __syncthreads();
  if (tid < 65 && h[tid] > 0) atomicAdd(&cnt[tid], h[tid]);
}

// ================= exclusive prefix -> base =================
__global__ void k_scan(const int* __restrict__ cnt, int* __restrict__ base) {
  if (threadIdx.x == 0) {
    int s = 0;
    for (int c = 0; c < 65; ++c) { base[c] = s; s += cnt[c]; }
  }
}

// ================= scatter row indices grouped by class =================
__global__ __launch_bounds__(256) void k_scatter(
    const int* __restrict__ preds, const int* __restrict__ base,
    int* __restrict__ cursor, int* __restrict__ rowidx) {
  __shared__ int h[65];      // per-block per-class count
  __shared__ int gb[65];     // per-block reserved global offset
  int tid = threadIdx.x;
  if (tid < 65) h[tid] = 0;
  __syncthreads();
  int i = blockIdx.x * 256 + tid;
  int c = preds[i];
  int pos = atomicAdd(&h[c], 1);     // rank within block for this class
  __syncthreads();
  if (tid < 65 && h[tid] > 0) gb[tid] = atomicAdd(&cursor[tid], h[tid]);
  __syncthreads();
  rowidx[base[c] + gb[c] + pos] = i;
}

// ================= segment sums: gather rows per class, register accumulate =================
__global__ __launch_bounds__(256) void k_segsum2(
    const float* __restrict__ feat, const int* __restrict__ rowidx,
    const int* __restrict__ base, const int* __restrict__ cnt,
    float* __restrict__ psum /* [8][65][2048] */) {
  int c = blockIdx.x;   // 0..64
  int j = blockIdx.y;   // 0..7
  int tid = threadIdx.x;
  int start = base[c], n = cnt[c];
  f32x4 a0 = {}, a1 = {};
  const float* fp = feat + (size_t)tid * 8;
  for (int i = j; i < n; i += 8) {
    int row = rowidx[start + i];
    const f32x4* p = (const f32x4*)(fp + (size_t)row * 2048);
    a0 += p[0];
    a1 += p[1];
  }
  float* o = psum + ((size_t)(j * 65 + c)) * 2048 + (size_t)tid * 8;
  *(f32x4*)o = a0;
  *(f32x4*)(o + 4) = a1;
}

// ================= centroids: reduce partials, normalize, split bf16; B^T layout [80][2048] =================
__global__ __launch_bounds__(256) void k_centroid(
    const float* __restrict__ psum, const int* __restrict__ pcnt,
    us* __restrict__ ch, us* __restrict__ cl) {
  int c = blockIdx.x;  // 0..79
  int tid = threadIdx.x;
  if (c >= 65) {
    for (int d = tid; d < 2048; d += 256) { ch[(size_t)c * 2048 + d] = 0; cl[(size_t)c * 2048 + d] = 0; }
    return;
  }
  int cnt = pcnt[c];
  float inv = 1.0f / (float)((cnt > 1) ? cnt : 1);
  float mean[8]; float sq = 0.f;
  for (int i = 0; i < 8; ++i) {
    int d = tid + i * 256;
    float s = 0.f;
    for (int nc = 0; nc < 8; ++nc) s += psum[((size_t)nc * 65 + c) * 2048 + d];
    mean[i] = s * inv;
    sq += mean[i] * mean[i];
  }
  __shared__ float red[256];
  red[tid] = sq; __syncthreads();
  for (int s = 128; s > 0; s >>= 1) { if (tid < s) red[tid] += red[tid + s]; __syncthreads(); }
  float norm = sqrtf(red[0]);
  float dscale = (cnt > 0) ? 1.0f / fmaxf(norm, 1e-12f) : 0.0f;
  for (int i = 0; i < 8; ++i) {
    int d = tid + i * 256;
    us hi, lo; splitbf(mean[i] * dscale, hi, lo);
    ch[(size_t)c * 2048 + d] = hi; cl[(size_t)c * 2048 + d] = lo;
  }
}

// ================= sim GEMM (64x80, K split in 2x1024, BK=64) -> partial sims =================
__global__ __launch_bounds__(256, 2) void k_sim(
    const us* __restrict__ Ah_, const us* __restrict__ Al_,   // feat planes [16384][2048]
    const us* __restrict__ Bh_, const us* __restrict__ Bl_,   // cent planes [80][2048]
    float* __restrict__ simbuf /* [2][16384][80] */) {
  __shared__ __align__(16) us sA[2][4096];
  __shared__ __align__(16) us sB[2][5120];
  int tid = threadIdx.x;
  int m0 = blockIdx.x * 64;
  int ks = blockIdx.y;             // K half
  int kbase = ks * 1024;
  int lane = tid & 63, wv = tid >> 6;
  int frow = lane & 15, fq = lane >> 4;
  int srow = tid >> 3;
  int scolsw = (((tid & 7) ^ ((tid >> 3) & 7)) * 8);
  f32x4 acc[5] = {};
  size_t arow = (size_t)(m0 + srow) * 2048 + kbase + scolsw;
  size_t brow = (size_t)srow * 2048 + kbase + scolsw;
  size_t brow2 = (size_t)(64 + (tid >> 3)) * 2048 + kbase + scolsw;
  for (int kt = 0; kt < 16; ++kt) {
    int k0 = kt * 64;
    __syncthreads();
#pragma unroll
    for (int j = 0; j < 2; ++j) {
      int lo = j * 2048 + wv * 512;
      size_t go = (size_t)j * 32 * 2048 + k0;
      GLD16(&sA[0][lo], Ah_ + arow + go);
      GLD16(&sA[1][lo], Al_ + arow + go);
      GLD16(&sB[0][lo], Bh_ + brow + go);
      GLD16(&sB[1][lo], Bl_ + brow + go);
    }
    if (wv < 2) {
      GLD16(&sB[0][4096 + wv * 512], Bh_ + brow2 + k0);
      GLD16(&sB[1][4096 + wv * 512], Bl_ + brow2 + k0);
    }
    __syncthreads();
#pragma unroll
    for (int s = 0; s < 2; ++s) {
      int ca = ((s * 4 + fq) ^ (frow & 7)) * 8;
      short8 a_h = *(const short8*)&sA[0][(wv * 16 + frow) * 64 + ca];
      short8 a_l = *(const short8*)&sA[1][(wv * 16 + frow) * 64 + ca];
#pragma unroll
      for (int fn = 0; fn < 5; ++fn) {
        short8 b_h = *(const short8*)&sB[0][(fn * 16 + frow) * 64 + ca];
        short8 b_l = *(const short8*)&sB[1][(fn * 16 + frow) * 64 + ca];
        acc[fn] = MFMA16(a_h, b_h, acc[fn]);
        acc[fn] = MFMA16(a_h, b_l, acc[fn]);
        acc[fn] = MFMA16(a_l, b_h, acc[fn]);
      }
    }
  }
#pragma unroll
  for (int fn = 0; fn < 5; ++fn) {
    int col = fn * 16 + (lane & 15);
#pragma unroll
    for (int r = 0; r < 4; ++r) {
      int row = wv * 16 + (lane >> 4) * 4 + r;
      simbuf[((size_t)(ks * 16384 + m0 + row)) * 80 + col] = acc[fn][r];
    }
  }
}

// ================= sim reduce: argmax over summed halves + CE gather =================
__global__ __launch_bounds__(256) void k_simred(
    const float* __restrict__ simbuf, const float* __restrict__ logp,
    float* __restrict__ accs /* [1]=ce */) {
  __shared__ float sred[256];
  int tid = threadIdx.x;
  int row = blockIdx.x * 256 + tid;
  const float* p0 = simbuf + (size_t)row * 80;
  const float* p1 = simbuf + (size_t)(16384 + row) * 80;
  float m = -1e30f; int am = 0;
  for (int c = 0; c < 65; ++c) {
    float v = p0[c] + p1[c];
    if (v > m) { m = v; am = c; }   // first-max: strict >
  }
  sred[tid] = logp[(size_t)row * 65 + am];
  __syncthreads();
  for (int s = 128; s > 0; s >>= 1) { if (tid < s) sred[tid] += sred[tid + s]; __syncthreads(); }
  if (tid == 0) atomicAdd(&accs[1], sred[0]);
}

// ================= final combine =================
__global__ void k_final(const float* __restrict__ accs, float* __restrict__ out) {
  __shared__ float red[256];
  int t = threadIdx.x;
  float d = 0.f;
  if (t < 65) {
    float mp = accs[2 + t] * (1.f / 16384.f);
    d = mp * logf(mp + 1e-6f);
  }
  red[t] = d; __syncthreads();
  for (int s = 128; s > 0; s >>= 1) { if (t < s) red[t] += red[t + s]; __syncthreads(); }
  if (t == 0) {
    float entropy = -accs[0] * (1.f / 16384.f);
    float ce = -accs[1] * (1.f / 16384.f);
    out[0] = entropy + red[0] + 0.3f * ce;
  }
}

extern "C" void kernel_launch(void* const* d_in, const int* in_sizes, int n_in,
                              void* d_out, int out_size, void* d_ws, size_t ws_size,
                              hipStream_t stream) {
  const float* feat = (const float*)d_in[0];
  const float* w1   = (const float*)d_in[1];
  const float* b1   = (const float*)d_in[2];
  const float* w2   = (const float*)d_in[3];
  const float* b2   = (const float*)d_in[4];
  float* out = (float*)d_out;

  char* w = (char*)d_ws;
  auto alloc = [&](size_t b) { char* p = w; w += (b + 255) & ~(size_t)255; return p; };
  us*  feat_hi = (us*)alloc(16384ull * 2048 * 2);
  us*  feat_lo = (us*)alloc(16384ull * 2048 * 2);
  us*  w1t_hi  = (us*)alloc(512ull * 2048 * 2);
  us*  w1t_lo  = (us*)alloc(512ull * 2048 * 2);
  us*  w2t_hi  = (us*)alloc(80ull * 512 * 2);
  us*  w2t_lo  = (us*)alloc(80ull * 512 * 2);
  u32* mask    = (u32*)alloc(262144ull * 4);
  us*  h_hi    = (us*)alloc(16384ull * 512 * 2);
  us*  h_lo    = (us*)alloc(16384ull * 512 * 2);
  float* logp  = (float*)alloc(16384ull * 65 * 4);
  int*   preds = (int*)alloc(16384ull * 4);
  float* psum  = (float*)alloc(8ull * 65 * 2048 * 4);
  int*   cnt   = (int*)alloc(65ull * 4);
  int*   base  = (int*)alloc(65ull * 4);
  int*   cursor= (int*)alloc(65ull * 4);
  int*   rowidx= (int*)alloc(16384ull * 4);
  us*  cent_hi = (us*)alloc(80ull * 2048 * 2);
  us*  cent_lo = (us*)alloc(80ull * 2048 * 2);
  float* simbuf= (float*)alloc(2ull * 16384 * 80 * 4);
  float* accs  = (float*)alloc(68ull * 4);

  k_init<<<1, 256, 0, stream>>>(accs, cnt, cursor);
  k_mask<<<512, 256, 0, stream>>>(mask);
  k_splitw1<<<dim3(32, 8), 256, 0, stream>>>(w1, w1t_hi, w1t_lo);
  k_splitw2<<<80, 256, 0, stream>>>(w2, w2t_hi, w2t_lo);
  k_splitfeat<<<16384, 256, 0, stream>>>(feat, feat_hi, feat_lo);
  k_gemm1<<<dim3(128, 4), 256, 0, stream>>>(feat_hi, feat_lo, w1t_hi, w1t_lo, b1, mask, h_hi, h_lo);
  k_gemm2<<<256, 256, 0, stream>>>(h_hi, h_lo, w2t_hi, w2t_lo, b2, logp, preds, accs);
  k_hist<<<64, 256, 0, stream>>>(preds, cnt);
  k_scan<<<1, 64, 0, stream>>>(cnt, base);
  k_scatter<<<64, 256, 0, stream>>>(preds, base, cursor, rowidx);
  k_segsum2<<<dim3(65, 8), 256, 0, stream>>>(feat, rowidx, base, cnt, psum);
  k_centroid<<<80, 256, 0, stream>>>(psum, cnt, cent_hi, cent_lo);
  k_sim<<<dim3(256, 2), 256, 0, stream>>>(feat_hi, feat_lo, cent_hi, cent_lo, simbuf);
  k_simred<<<64, 256, 0, stream>>>(simbuf, logp, accs);
  k_final<<<1, 256, 0, stream>>>(accs, out);
}

// Round 4
// 486.274 us; speedup vs baseline: 1.3375x; 1.0993x over previous
//
#include <hip/hip_runtime.h>

typedef unsigned short us;
typedef unsigned int u32;
typedef __attribute__((ext_vector_type(8))) short short8;
typedef __attribute__((ext_vector_type(4))) float f32x4;

#define MFMA16(a, b, c) __builtin_amdgcn_mfma_f32_16x16x32_bf16((a), (b), (c), 0, 0, 0)

// async global->LDS, 16B per lane; lds ptr must be wave-uniform
#define GLD16(lptr, gptr) __builtin_amdgcn_global_load_lds( \
    (__attribute__((address_space(1))) void*)(gptr), \
    (__attribute__((address_space(3))) void*)(lptr), 16, 0, 0)

// ---- bf16 split helpers (RNE via bit trick; no NaN inputs here) ----
__device__ inline us f2bf(float f) {
  u32 u = __float_as_uint(f);
  u32 r = (u + 0x7FFFu + ((u >> 16) & 1u)) >> 16;
  return (us)r;
}
__device__ inline float bf2f(us s) { return __uint_as_float((u32)s << 16); }
__device__ inline void splitbf(float x, us& hi, us& lo) {
  hi = f2bf(x);
  lo = f2bf(x - bf2f(hi));
}

// ================= PREP: splitfeat + mask + splitw1 + splitw2 + init, one launch =================
#define TF_R(a) { x0 += x1; x1 = (x1 << (a)) | (x1 >> (32 - (a))); x1 ^= x0; }
__global__ __launch_bounds__(256) void k_prep(
    const float* __restrict__ feat, const float* __restrict__ w1, const float* __restrict__ w2,
    us* __restrict__ xh, us* __restrict__ xl,
    us* __restrict__ w1h, us* __restrict__ w1l,
    us* __restrict__ w2h, us* __restrict__ w2l,
    u32* __restrict__ mask, float* __restrict__ accs,
    int* __restrict__ cnt, int* __restrict__ cursor, int* __restrict__ done) {
  __shared__ float tile[64][65];
  int b = blockIdx.x, t = threadIdx.x;
  if (b < 16384) {
    // ---- split feat fp32 -> hi/lo bf16 planes ----
    size_t g = ((size_t)b * 256 + t) * 8;
    f32x4 a = *(const f32x4*)(feat + g);
    f32x4 bb = *(const f32x4*)(feat + g + 4);
    short8 h8, l8;
    for (int i = 0; i < 4; ++i) {
      us hi, lo;
      splitbf(a[i], hi, lo); h8[i] = (short)hi; l8[i] = (short)lo;
      splitbf(bb[i], hi, lo); h8[4 + i] = (short)hi; l8[4 + i] = (short)lo;
    }
    *(short8*)(xh + g) = h8;
    *(short8*)(xl + g) = l8;
  } else if (b < 16896) {
    // ---- dropout mask: JAX threefry2x32, key (0,42) ----
    u32 tt = (u32)(b - 16384) * 256u + (u32)t;  // 0..131071
    const u32 K0 = 0u, K1 = 42u, K2 = 0x1BD11BDAu ^ 0u ^ 42u;
    u32 w0 = 0, w1r = 0;
    for (int i = 0; i < 32; ++i) {
      u32 x0 = tt * 32u + (u32)i;
      u32 x1 = x0 + 4194304u;
      x0 += K0; x1 += K1;
      TF_R(13) TF_R(15) TF_R(26) TF_R(6)   x0 += K1; x1 += K2 + 1u;
      TF_R(17) TF_R(29) TF_R(16) TF_R(24)  x0 += K2; x1 += K0 + 2u;
      TF_R(13) TF_R(15) TF_R(26) TF_R(6)   x0 += K0; x1 += K1 + 3u;
      TF_R(17) TF_R(29) TF_R(16) TF_R(24)  x0 += K1; x1 += K2 + 4u;
      TF_R(13) TF_R(15) TF_R(26) TF_R(6)   x0 += K2; x1 += K0 + 5u;
      w0 |= (u32)((x0 >> 31) == 0u) << i;  // uniform<0.5  <=>  top bit 0
      w1r |= (u32)((x1 >> 31) == 0u) << i;
    }
    mask[tt] = w0;
    mask[tt + 131072u] = w1r;
  } else if (b < 17152) {
    // ---- split+transpose w1 [2048][512] -> planes [512][2048] ----
    int i = b - 16896;
    int k0 = (i & 31) * 64, n0 = (i >> 5) * 64;
    int cr = t >> 6, cc = t & 63;
    for (int j = 0; j < 16; ++j) {
      int r = j * 4 + cr;
      tile[r][cc] = w1[(size_t)(k0 + r) * 512 + n0 + cc];
    }
    __syncthreads();
    for (int j = 0; j < 16; ++j) {
      int n = j * 4 + cr;
      int k = cc;
      us hi, lo; splitbf(tile[k][n], hi, lo);
      size_t o = (size_t)(n0 + n) * 2048 + k0 + k;
      w1h[o] = hi; w1l[o] = lo;
    }
  } else if (b < 17232) {
    // ---- split+transpose w2 [512][65] -> planes [80][512] (pad zero) ----
    int n = b - 17152;
    for (int k = t; k < 512; k += 256) {
      float v = (n < 65) ? w2[(size_t)k * 65 + n] : 0.f;
      us hi, lo; splitbf(v, hi, lo);
      w2h[n * 512 + k] = hi; w2l[n * 512 + k] = lo;
    }
  } else {
    // ---- init small accumulators ----
    if (t < 68) accs[t] = 0.f;
    if (t < 65) { cnt[t] = 0; cursor[t] = 0; }
    if (t == 0) done[0] = 0;
  }
}

// ================= GEMM1: h = dropout(relu(feat@w1 + b1)), bf16x3, 128x128x64 =================
// grid dim3(128,4): bm = blockIdx.x so the 4 N-blocks sharing an A panel land on the same XCD.
// LDS layout [row][64] with k-chunk XOR swizzle (chunk ^ row&7) -> 2-way banks (free).
__global__ __launch_bounds__(256, 2) void k_gemm1(
    const us* __restrict__ Ah_, const us* __restrict__ Al_,   // feat planes [16384][2048]
    const us* __restrict__ Bh_, const us* __restrict__ Bl_,   // w1t planes  [512][2048]
    const float* __restrict__ b1, const u32* __restrict__ mask,
    us* __restrict__ Hh, us* __restrict__ Hl) {
  __shared__ __align__(16) us lds[4 * 8192];  // Ah, Al, Bh, Bl tiles [128][64]
  us* sAh = lds; us* sAl = lds + 8192; us* sBh = lds + 16384; us* sBl = lds + 24576;
  int tid = threadIdx.x;
  int bm = blockIdx.x, bn = blockIdx.y;
  int m0 = bm * 128, n0 = bn * 128;
  int lane = tid & 63, wv = tid >> 6;
  int wm = (wv >> 1) * 64, wn = (wv & 1) * 64;
  int frow = lane & 15, fq = lane >> 4;      // fq: 16B k-chunk within 32-us half
  int srow = tid >> 3;                        // 0..31 (rows per staging call)
  int scolsw = (((tid & 7) ^ ((tid >> 3) & 7)) * 8);  // swizzled source chunk
  f32x4 acc[4][4] = {};
  size_t arow = (size_t)(m0 + srow) * 2048 + scolsw;
  size_t brow = (size_t)(n0 + srow) * 2048 + scolsw;
  for (int kt = 0; kt < 32; ++kt) {
    int k0 = kt * 64;
    __syncthreads();
#pragma unroll
    for (int j = 0; j < 4; ++j) {
      int lo = j * 2048 + wv * 512;
      size_t go = (size_t)j * 32 * 2048 + k0;
      GLD16(sAh + lo, Ah_ + arow + go);
      GLD16(sAl + lo, Al_ + arow + go);
      GLD16(sBh + lo, Bh_ + brow + go);
      GLD16(sBl + lo, Bl_ + brow + go);
    }
    __syncthreads();
#pragma unroll
    for (int s = 0; s < 2; ++s) {
      short8 ah[4], al[4], bh[4], bl[4];
#pragma unroll
      for (int f = 0; f < 4; ++f) {
        int ca = ((s * 4 + fq) ^ (frow & 7)) * 8;
        int ra = (wm + f * 16 + frow) * 64 + ca;
        int rb = (wn + f * 16 + frow) * 64 + ca;
        ah[f] = *(const short8*)&sAh[ra];
        al[f] = *(const short8*)&sAl[ra];
        bh[f] = *(const short8*)&sBh[rb];
        bl[f] = *(const short8*)&sBl[rb];
      }
#pragma unroll
      for (int i = 0; i < 4; ++i)
#pragma unroll
        for (int j2 = 0; j2 < 4; ++j2) {
          acc[i][j2] = MFMA16(ah[i], bh[j2], acc[i][j2]);
          acc[i][j2] = MFMA16(ah[i], bl[j2], acc[i][j2]);
          acc[i][j2] = MFMA16(al[i], bh[j2], acc[i][j2]);
        }
    }
  }
  // epilogue: +b1, relu, dropout, split to bf16 hi/lo
#pragma unroll
  for (int i = 0; i < 4; ++i)
#pragma unroll
    for (int j = 0; j < 4; ++j)
#pragma unroll
      for (int r = 0; r < 4; ++r) {
        int row = m0 + wm + i * 16 + (lane >> 4) * 4 + r;
        int col = n0 + wn + j * 16 + (lane & 15);
        float v = acc[i][j][r] + b1[col];
        v = fmaxf(v, 0.f);
        u32 f = (u32)row * 512u + (u32)col;
        u32 keep = (mask[f >> 5] >> (f & 31u)) & 1u;
        v = keep ? v * 2.f : 0.f;
        us hi, lo; splitbf(v, hi, lo);
        size_t o = (size_t)row * 512 + col;
        Hh[o] = hi; Hl[o] = lo;
      }
}

// ================= GEMM2 (64x80, K=512, BK=64) + fused softmax stats + fused hist =================
__global__ __launch_bounds__(256, 2) void k_gemm2(
    const us* __restrict__ Ah_, const us* __restrict__ Al_,   // h planes [16384][512]
    const us* __restrict__ Bh_, const us* __restrict__ Bl_,   // w2t planes [80][512]
    const float* __restrict__ b2,
    float* __restrict__ logp, int* __restrict__ preds,
    float* __restrict__ accs /* [0] ent, [2..] mp */, int* __restrict__ cnt) {
  __shared__ __align__(16) us sA[2][4096];   // [64][64] hi/lo
  __shared__ __align__(16) us sB[2][5120];   // [80][64] hi/lo
  __shared__ float slog[64 * 81];
  __shared__ float sm[64], sl[64];
  __shared__ float sred[256];
  __shared__ int hh[65];
  int tid = threadIdx.x;
  int m0 = blockIdx.x * 64;
  int lane = tid & 63, wv = tid >> 6;
  int frow = lane & 15, fq = lane >> 4;
  int srow = tid >> 3;
  int scolsw = (((tid & 7) ^ ((tid >> 3) & 7)) * 8);
  f32x4 acc[5] = {};
  size_t arow = (size_t)(m0 + srow) * 512 + scolsw;
  size_t brow = (size_t)srow * 512 + scolsw;
  size_t brow2 = (size_t)(64 + (tid >> 3)) * 512 + scolsw;  // rows 64..79 (tid<128)
  for (int kt = 0; kt < 8; ++kt) {
    int k0 = kt * 64;
    __syncthreads();
#pragma unroll
    for (int j = 0; j < 2; ++j) {
      int lo = j * 2048 + wv * 512;
      size_t go = (size_t)j * 32 * 512 + k0;
      GLD16(&sA[0][lo], Ah_ + arow + go);
      GLD16(&sA[1][lo], Al_ + arow + go);
      GLD16(&sB[0][lo], Bh_ + brow + go);
      GLD16(&sB[1][lo], Bl_ + brow + go);
    }
    if (wv < 2) {
      GLD16(&sB[0][4096 + wv * 512], Bh_ + brow2 + k0);
      GLD16(&sB[1][4096 + wv * 512], Bl_ + brow2 + k0);
    }
    __syncthreads();
#pragma unroll
    for (int s = 0; s < 2; ++s) {
      int ca = ((s * 4 + fq) ^ (frow & 7)) * 8;
      short8 a_h = *(const short8*)&sA[0][(wv * 16 + frow) * 64 + ca];
      short8 a_l = *(const short8*)&sA[1][(wv * 16 + frow) * 64 + ca];
#pragma unroll
      for (int fn = 0; fn < 5; ++fn) {
        short8 b_h = *(const short8*)&sB[0][(fn * 16 + frow) * 64 + ca];
        short8 b_l = *(const short8*)&sB[1][(fn * 16 + frow) * 64 + ca];
        acc[fn] = MFMA16(a_h, b_h, acc[fn]);
        acc[fn] = MFMA16(a_h, b_l, acc[fn]);
        acc[fn] = MFMA16(a_l, b_h, acc[fn]);
      }
    }
  }
  // logits -> LDS (+bias)
#pragma unroll
  for (int fn = 0; fn < 5; ++fn) {
    int col = fn * 16 + (lane & 15);
    if (col < 65) {
      float bb = b2[col];
#pragma unroll
      for (int r = 0; r < 4; ++r) {
        int row = wv * 16 + (lane >> 4) * 4 + r;
        slog[row * 81 + col] = acc[fn][r] + bb;
      }
    }
  }
  if (tid < 65) hh[tid] = 0;
  __syncthreads();
  if (tid < 64) {
    int row = tid;
    float m = -1e30f; int am = 0;
    for (int c = 0; c < 65; ++c) {
      float v = slog[row * 81 + c];
      if (v > m) { m = v; am = c; }   // first-max: strict >
    }
    float s = 0.f;
    for (int c = 0; c < 65; ++c) s += expf(slog[row * 81 + c] - m);
    sm[row] = m; sl[row] = logf(s);
    preds[m0 + row] = am;
    atomicAdd(&hh[am], 1);
  }
  __syncthreads();
  if (tid < 65 && hh[tid] > 0) atomicAdd(&cnt[tid], hh[tid]);
  float entp = 0.f;
  if (tid < 240) {
    int c = tid % 80, rr0 = tid / 80;
    if (c < 65) {
      float mpp = 0.f;
      for (int r = rr0; r < 64; r += 3) {
        float v = slog[r * 81 + c] - sm[r] - sl[r];
        logp[(size_t)(m0 + r) * 65 + c] = v;
        float p = expf(v);
        mpp += p;
        entp += p * logf(p + 1e-6f);
      }
      atomicAdd(&accs[2 + c], mpp);
    }
  }
  sred[tid] = entp;
  __syncthreads();
  for (int s = 128; s > 0; s >>= 1) { if (tid < s) sred[tid] += sred[tid + s]; __syncthreads(); }
  if (tid == 0) atomicAdd(&accs[0], sred[0]);
}

// ================= scatter row indices grouped by class (local prefix scan inside) =================
__global__ __launch_bounds__(256) void k_scatter(
    const int* __restrict__ preds, const int* __restrict__ cnt,
    int* __restrict__ cursor, int* __restrict__ rowidx) {
  __shared__ int h[65];      // per-block per-class count
  __shared__ int gb[65];     // per-block reserved global offset
  __shared__ int sbase[65];  // exclusive prefix of cnt
  int tid = threadIdx.x;
  if (tid < 65) { h[tid] = 0; sbase[tid] = cnt[tid]; }
  __syncthreads();
  int i = blockIdx.x * 256 + tid;
  int c = preds[i];
  int pos = atomicAdd(&h[c], 1);     // rank within block for this class
  if (tid == 0) {
    int s = 0;
    for (int cc = 0; cc < 65; ++cc) { int v = sbase[cc]; sbase[cc] = s; s += v; }
  }
  __syncthreads();
  if (tid < 65 && h[tid] > 0) gb[tid] = atomicAdd(&cursor[tid], h[tid]);
  __syncthreads();
  rowidx[sbase[c] + gb[c] + pos] = i;
}

// ================= segment sums: gather rows per class, register accumulate =================
__global__ __launch_bounds__(256) void k_segsum2(
    const float* __restrict__ feat, const int* __restrict__ rowidx,
    const int* __restrict__ cnt,
    float* __restrict__ psum /* [8][65][2048] */) {
  int c = blockIdx.x;   // 0..64
  int j = blockIdx.y;   // 0..7
  int tid = threadIdx.x;
  int start = 0;
  for (int cc = 0; cc < 65; ++cc) { if (cc == c) break; start += cnt[cc]; }
  int n = cnt[c];
  f32x4 a0 = {}, a1 = {};
  const float* fp = feat + (size_t)tid * 8;
  for (int i = j; i < n; i += 8) {
    int row = rowidx[start + i];
    const f32x4* p = (const f32x4*)(fp + (size_t)row * 2048);
    a0 += p[0];
    a1 += p[1];
  }
  float* o = psum + ((size_t)(j * 65 + c)) * 2048 + (size_t)tid * 8;
  *(f32x4*)o = a0;
  *(f32x4*)(o + 4) = a1;
}

// ================= centroids: reduce partials, normalize, split bf16; B^T layout [80][2048] =================
__global__ __launch_bounds__(256) void k_centroid(
    const float* __restrict__ psum, const int* __restrict__ pcnt,
    us* __restrict__ ch, us* __restrict__ cl) {
  int c = blockIdx.x;  // 0..79
  int tid = threadIdx.x;
  if (c >= 65) {
    for (int d = tid; d < 2048; d += 256) { ch[(size_t)c * 2048 + d] = 0; cl[(size_t)c * 2048 + d] = 0; }
    return;
  }
  int cnt = pcnt[c];
  float inv = 1.0f / (float)((cnt > 1) ? cnt : 1);
  float mean[8]; float sq = 0.f;
  for (int i = 0; i < 8; ++i) {
    int d = tid + i * 256;
    float s = 0.f;
    for (int nc = 0; nc < 8; ++nc) s += psum[((size_t)nc * 65 + c) * 2048 + d];
    mean[i] = s * inv;
    sq += mean[i] * mean[i];
  }
  __shared__ float red[256];
  red[tid] = sq; __syncthreads();
  for (int s = 128; s > 0; s >>= 1) { if (tid < s) red[tid] += red[tid + s]; __syncthreads(); }
  float norm = sqrtf(red[0]);
  float dscale = (cnt > 0) ? 1.0f / fmaxf(norm, 1e-12f) : 0.0f;
  for (int i = 0; i < 8; ++i) {
    int d = tid + i * 256;
    us hi, lo; splitbf(mean[i] * dscale, hi, lo);
    ch[(size_t)c * 2048 + d] = hi; cl[(size_t)c * 2048 + d] = lo;
  }
}

// ================= sim GEMM (64x80, K split in 2x1024, BK=64) -> partial sims =================
__global__ __launch_bounds__(256, 2) void k_sim(
    const us* __restrict__ Ah_, const us* __restrict__ Al_,   // feat planes [16384][2048]
    const us* __restrict__ Bh_, const us* __restrict__ Bl_,   // cent planes [80][2048]
    float* __restrict__ simbuf /* [2][16384][80] */) {
  __shared__ __align__(16) us sA[2][4096];
  __shared__ __align__(16) us sB[2][5120];
  int tid = threadIdx.x;
  int m0 = blockIdx.x * 64;
  int ks = blockIdx.y;             // K half
  int kbase = ks * 1024;
  int lane = tid & 63, wv = tid >> 6;
  int frow = lane & 15, fq = lane >> 4;
  int srow = tid >> 3;
  int scolsw = (((tid & 7) ^ ((tid >> 3) & 7)) * 8);
  f32x4 acc[5] = {};
  size_t arow = (size_t)(m0 + srow) * 2048 + kbase + scolsw;
  size_t brow = (size_t)srow * 2048 + kbase + scolsw;
  size_t brow2 = (size_t)(64 + (tid >> 3)) * 2048 + kbase + scolsw;
  for (int kt = 0; kt < 16; ++kt) {
    int k0 = kt * 64;
    __syncthreads();
#pragma unroll
    for (int j = 0; j < 2; ++j) {
      int lo = j * 2048 + wv * 512;
      size_t go = (size_t)j * 32 * 2048 + k0;
      GLD16(&sA[0][lo], Ah_ + arow + go);
      GLD16(&sA[1][lo], Al_ + arow + go);
      GLD16(&sB[0][lo], Bh_ + brow + go);
      GLD16(&sB[1][lo], Bl_ + brow + go);
    }
    if (wv < 2) {
      GLD16(&sB[0][4096 + wv * 512], Bh_ + brow2 + k0);
      GLD16(&sB[1][4096 + wv * 512], Bl_ + brow2 + k0);
    }
    __syncthreads();
#pragma unroll
    for (int s = 0; s < 2; ++s) {
      int ca = ((s * 4 + fq) ^ (frow & 7)) * 8;
      short8 a_h = *(const short8*)&sA[0][(wv * 16 + frow) * 64 + ca];
      short8 a_l = *(const short8*)&sA[1][(wv * 16 + frow) * 64 + ca];
#pragma unroll
      for (int fn = 0; fn < 5; ++fn) {
        short8 b_h = *(const short8*)&sB[0][(fn * 16 + frow) * 64 + ca];
        short8 b_l = *(const short8*)&sB[1][(fn * 16 + frow) * 64 + ca];
        acc[fn] = MFMA16(a_h, b_h, acc[fn]);
        acc[fn] = MFMA16(a_h, b_l, acc[fn]);
        acc[fn] = MFMA16(a_l, b_h, acc[fn]);
      }
    }
  }
#pragma unroll
  for (int fn = 0; fn < 5; ++fn) {
    int col = fn * 16 + (lane & 15);
#pragma unroll
    for (int r = 0; r < 4; ++r) {
      int row = wv * 16 + (lane >> 4) * 4 + r;
      simbuf[((size_t)(ks * 16384 + m0 + row)) * 80 + col] = acc[fn][r];
    }
  }
}

// ================= sim reduce + CE gather + (last block) final combine =================
__global__ __launch_bounds__(256) void k_simred(
    const float* __restrict__ simbuf, const float* __restrict__ logp,
    float* __restrict__ accs, int* __restrict__ done, float* __restrict__ out) {
  __shared__ float sred[256];
  __shared__ int lastflag;
  int tid = threadIdx.x;
  int row = blockIdx.x * 256 + tid;
  const float* p0 = simbuf + (size_t)row * 80;
  const float* p1 = simbuf + (size_t)(16384 + row) * 80;
  float m = -1e30f; int am = 0;
  for (int c = 0; c < 65; ++c) {
    float v = p0[c] + p1[c];
    if (v > m) { m = v; am = c; }   // first-max: strict >
  }
  sred[tid] = logp[(size_t)row * 65 + am];
  __syncthreads();
  for (int s = 128; s > 0; s >>= 1) { if (tid < s) sred[tid] += sred[tid + s]; __syncthreads(); }
  if (tid == 0) {
    atomicAdd(&accs[1], sred[0]);
    __threadfence();
    int old = atomicAdd(done, 1);
    lastflag = (old == 63);
  }
  __syncthreads();
  if (!lastflag) return;
  // last block: final combine. All accs reads via device-scope atomic RMW (cross-XCD safe).
  float d = 0.f;
  if (tid < 65) {
    float mp = atomicAdd(&accs[2 + tid], 0.f) * (1.f / 16384.f);
    d = mp * logf(mp + 1e-6f);
  }
  sred[tid] = d;
  __syncthreads();
  for (int s = 128; s > 0; s >>= 1) { if (tid < s) sred[tid] += sred[tid + s]; __syncthreads(); }
  if (tid == 0) {
    float entropy = -atomicAdd(&accs[0], 0.f) * (1.f / 16384.f);
    float ce = -atomicAdd(&accs[1], 0.f) * (1.f / 16384.f);
    out[0] = entropy + sred[0] + 0.3f * ce;
  }
}

extern "C" void kernel_launch(void* const* d_in, const int* in_sizes, int n_in,
                              void* d_out, int out_size, void* d_ws, size_t ws_size,
                              hipStream_t stream) {
  const float* feat = (const float*)d_in[0];
  const float* w1   = (const float*)d_in[1];
  const float* b1   = (const float*)d_in[2];
  const float* w2   = (const float*)d_in[3];
  const float* b2   = (const float*)d_in[4];
  float* out = (float*)d_out;

  char* w = (char*)d_ws;
  auto alloc = [&](size_t b) { char* p = w; w += (b + 255) & ~(size_t)255; return p; };
  us*  feat_hi = (us*)alloc(16384ull * 2048 * 2);
  us*  feat_lo = (us*)alloc(16384ull * 2048 * 2);
  us*  w1t_hi  = (us*)alloc(512ull * 2048 * 2);
  us*  w1t_lo  = (us*)alloc(512ull * 2048 * 2);
  us*  w2t_hi  = (us*)alloc(80ull * 512 * 2);
  us*  w2t_lo  = (us*)alloc(80ull * 512 * 2);
  u32* mask    = (u32*)alloc(262144ull * 4);
  us*  h_hi    = (us*)alloc(16384ull * 512 * 2);
  us*  h_lo    = (us*)alloc(16384ull * 512 * 2);
  float* logp  = (float*)alloc(16384ull * 65 * 4);
  int*   preds = (int*)alloc(16384ull * 4);
  float* psum  = (float*)alloc(8ull * 65 * 2048 * 4);
  int*   cnt   = (int*)alloc(65ull * 4);
  int*   cursor= (int*)alloc(65ull * 4);
  int*   rowidx= (int*)alloc(16384ull * 4);
  us*  cent_hi = (us*)alloc(80ull * 2048 * 2);
  us*  cent_lo = (us*)alloc(80ull * 2048 * 2);
  float* simbuf= (float*)alloc(2ull * 16384 * 80 * 4);
  float* accs  = (float*)alloc(68ull * 4);
  int*   done  = (int*)alloc(4ull);

  k_prep<<<17233, 256, 0, stream>>>(feat, w1, w2, feat_hi, feat_lo,
                                    w1t_hi, w1t_lo, w2t_hi, w2t_lo,
                                    mask, accs, cnt, cursor, done);
  k_gemm1<<<dim3(128, 4), 256, 0, stream>>>(feat_hi, feat_lo, w1t_hi, w1t_lo, b1, mask, h_hi, h_lo);
  k_gemm2<<<256, 256, 0, stream>>>(h_hi, h_lo, w2t_hi, w2t_lo, b2, logp, preds, accs, cnt);
  k_scatter<<<64, 256, 0, stream>>>(preds, cnt, cursor, rowidx);
  k_segsum2<<<dim3(65, 8), 256, 0, stream>>>(feat, rowidx, cnt, psum);
  k_centroid<<<80, 256, 0, stream>>>(psum, cnt, cent_hi, cent_lo);
  k_sim<<<dim3(256, 2), 256, 0, stream>>>(feat_hi, feat_lo, cent_hi, cent_lo, simbuf);
  k_simred<<<64, 256, 0, stream>>>(simbuf, logp, accs, done, out);
}

// Round 5
// 478.573 us; speedup vs baseline: 1.3590x; 1.0161x over previous
//
#include <hip/hip_runtime.h>

typedef unsigned short us;
typedef unsigned int u32;
typedef __attribute__((ext_vector_type(8))) short short8;
typedef __attribute__((ext_vector_type(4))) float f32x4;

#define MFMA16(a, b, c) __builtin_amdgcn_mfma_f32_16x16x32_bf16((a), (b), (c), 0, 0, 0)

// async global->LDS, 16B per lane; lds ptr must be wave-uniform
#define GLD16(lptr, gptr) __builtin_amdgcn_global_load_lds( \
    (__attribute__((address_space(1))) void*)(gptr), \
    (__attribute__((address_space(3))) void*)(lptr), 16, 0, 0)

// ---- bf16 split helpers (RNE via bit trick; no NaN inputs here) ----
__device__ inline us f2bf(float f) {
  u32 u = __float_as_uint(f);
  u32 r = (u + 0x7FFFu + ((u >> 16) & 1u)) >> 16;
  return (us)r;
}
__device__ inline float bf2f(us s) { return __uint_as_float((u32)s << 16); }
__device__ inline void splitbf(float x, us& hi, us& lo) {
  hi = f2bf(x);
  lo = f2bf(x - bf2f(hi));
}

// ================= PREP: splitfeat + mask + splitw1 + splitw2 + init, one launch =================
#define TF_R(a) { x0 += x1; x1 = (x1 << (a)) | (x1 >> (32 - (a))); x1 ^= x0; }
__global__ __launch_bounds__(256) void k_prep(
    const float* __restrict__ feat, const float* __restrict__ w1, const float* __restrict__ w2,
    us* __restrict__ xh, us* __restrict__ xl,
    us* __restrict__ w1h, us* __restrict__ w1l,
    us* __restrict__ w2h, us* __restrict__ w2l,
    u32* __restrict__ mask, float* __restrict__ accs,
    int* __restrict__ cnt, int* __restrict__ cursor, int* __restrict__ done) {
  __shared__ float tile[64][65];
  int b = blockIdx.x, t = threadIdx.x;
  if (b < 16384) {
    // ---- split feat fp32 -> hi/lo bf16 planes ----
    size_t g = ((size_t)b * 256 + t) * 8;
    f32x4 a = *(const f32x4*)(feat + g);
    f32x4 bb = *(const f32x4*)(feat + g + 4);
    short8 h8, l8;
    for (int i = 0; i < 4; ++i) {
      us hi, lo;
      splitbf(a[i], hi, lo); h8[i] = (short)hi; l8[i] = (short)lo;
      splitbf(bb[i], hi, lo); h8[4 + i] = (short)hi; l8[4 + i] = (short)lo;
    }
    *(short8*)(xh + g) = h8;
    *(short8*)(xl + g) = l8;
  } else if (b < 16896) {
    // ---- dropout mask: JAX threefry2x32, key (0,42) ----
    u32 tt = (u32)(b - 16384) * 256u + (u32)t;  // 0..131071
    const u32 K0 = 0u, K1 = 42u, K2 = 0x1BD11BDAu ^ 0u ^ 42u;
    u32 w0 = 0, w1r = 0;
    for (int i = 0; i < 32; ++i) {
      u32 x0 = tt * 32u + (u32)i;
      u32 x1 = x0 + 4194304u;
      x0 += K0; x1 += K1;
      TF_R(13) TF_R(15) TF_R(26) TF_R(6)   x0 += K1; x1 += K2 + 1u;
      TF_R(17) TF_R(29) TF_R(16) TF_R(24)  x0 += K2; x1 += K0 + 2u;
      TF_R(13) TF_R(15) TF_R(26) TF_R(6)   x0 += K0; x1 += K1 + 3u;
      TF_R(17) TF_R(29) TF_R(16) TF_R(24)  x0 += K1; x1 += K2 + 4u;
      TF_R(13) TF_R(15) TF_R(26) TF_R(6)   x0 += K2; x1 += K0 + 5u;
      w0 |= (u32)((x0 >> 31) == 0u) << i;  // uniform<0.5  <=>  top bit 0
      w1r |= (u32)((x1 >> 31) == 0u) << i;
    }
    mask[tt] = w0;
    mask[tt + 131072u] = w1r;
  } else if (b < 17152) {
    // ---- split+transpose w1 [2048][512] -> planes [512][2048] ----
    int i = b - 16896;
    int k0 = (i & 31) * 64, n0 = (i >> 5) * 64;
    int cr = t >> 6, cc = t & 63;
    for (int j = 0; j < 16; ++j) {
      int r = j * 4 + cr;
      tile[r][cc] = w1[(size_t)(k0 + r) * 512 + n0 + cc];
    }
    __syncthreads();
    for (int j = 0; j < 16; ++j) {
      int n = j * 4 + cr;
      int k = cc;
      us hi, lo; splitbf(tile[k][n], hi, lo);
      size_t o = (size_t)(n0 + n) * 2048 + k0 + k;
      w1h[o] = hi; w1l[o] = lo;
    }
  } else if (b < 17232) {
    // ---- split+transpose w2 [512][65] -> planes [80][512] (pad zero) ----
    int n = b - 17152;
    for (int k = t; k < 512; k += 256) {
      float v = (n < 65) ? w2[(size_t)k * 65 + n] : 0.f;
      us hi, lo; splitbf(v, hi, lo);
      w2h[n * 512 + k] = hi; w2l[n * 512 + k] = lo;
    }
  } else {
    // ---- init small accumulators ----
    if (t < 68) accs[t] = 0.f;
    if (t < 65) { cnt[t] = 0; cursor[t] = 0; }
    if (t == 0) done[0] = 0;
  }
}

// ================= GEMM1: h = dropout(relu(feat@w1+b1)) fused with fc2 partial logits ===========
// Main loop: bf16x3, 128x128x64, XOR-swizzled LDS. Epilogue: h tile -> LDS (A-layout),
// mini-GEMM vs w2 chunk (global, L2-hot) -> fp32 partial logits per bn (no atomics).
__global__ __launch_bounds__(256, 2) void k_gemm1(
    const us* __restrict__ Ah_, const us* __restrict__ Al_,   // feat planes [16384][2048]
    const us* __restrict__ Bh_, const us* __restrict__ Bl_,   // w1t planes  [512][2048]
    const float* __restrict__ b1, const u32* __restrict__ mask,
    const us* __restrict__ W2h_, const us* __restrict__ W2l_, // w2t planes [80][512]
    float* __restrict__ logitsP /* [4][16384][80] */) {
  __shared__ __align__(16) us lds[4 * 8192];  // Ah, Al, Bh, Bl tiles [128][64]
  us* sAh = lds; us* sAl = lds + 8192; us* sBh = lds + 16384; us* sBl = lds + 24576;
  int tid = threadIdx.x;
  int bm = blockIdx.x, bn = blockIdx.y;
  int m0 = bm * 128, n0 = bn * 128;
  int lane = tid & 63, wv = tid >> 6;
  int wm = (wv >> 1) * 64, wn = (wv & 1) * 64;
  int frow = lane & 15, fq = lane >> 4;      // fq: 16B k-chunk within 32-us half
  int quad = lane >> 4;
  int srow = tid >> 3;                        // 0..31 (rows per staging call)
  int scolsw = (((tid & 7) ^ ((tid >> 3) & 7)) * 8);  // swizzled source chunk
  f32x4 acc[4][4] = {};
  size_t arow = (size_t)(m0 + srow) * 2048 + scolsw;
  size_t brow = (size_t)(n0 + srow) * 2048 + scolsw;
  for (int kt = 0; kt < 32; ++kt) {
    int k0 = kt * 64;
    __syncthreads();
#pragma unroll
    for (int j = 0; j < 4; ++j) {
      int lo = j * 2048 + wv * 512;
      size_t go = (size_t)j * 32 * 2048 + k0;
      GLD16(sAh + lo, Ah_ + arow + go);
      GLD16(sAl + lo, Al_ + arow + go);
      GLD16(sBh + lo, Bh_ + brow + go);
      GLD16(sBl + lo, Bl_ + brow + go);
    }
    __syncthreads();
#pragma unroll
    for (int s = 0; s < 2; ++s) {
      short8 ah[4], al[4], bh[4], bl[4];
#pragma unroll
      for (int f = 0; f < 4; ++f) {
        int ca = ((s * 4 + fq) ^ (frow & 7)) * 8;
        int ra = (wm + f * 16 + frow) * 64 + ca;
        int rb = (wn + f * 16 + frow) * 64 + ca;
        ah[f] = *(const short8*)&sAh[ra];
        al[f] = *(const short8*)&sAl[ra];
        bh[f] = *(const short8*)&sBh[rb];
        bl[f] = *(const short8*)&sBl[rb];
      }
#pragma unroll
      for (int i = 0; i < 4; ++i)
#pragma unroll
        for (int j2 = 0; j2 < 4; ++j2) {
          acc[i][j2] = MFMA16(ah[i], bh[j2], acc[i][j2]);
          acc[i][j2] = MFMA16(ah[i], bl[j2], acc[i][j2]);
          acc[i][j2] = MFMA16(al[i], bh[j2], acc[i][j2]);
        }
    }
  }
  // ---- epilogue: +b1, relu, dropout, split bf16, write h tile into LDS in A-frag layout ----
  __syncthreads();  // all fragment reads of staging LDS are done
  us* sHh = lds;             // [2 slabs][128 rows][64] swizzled, 32 KB
  us* sHl = lds + 16384;     // 32 KB
#pragma unroll
  for (int i = 0; i < 4; ++i)
#pragma unroll
    for (int j = 0; j < 4; ++j)
#pragma unroll
      for (int r = 0; r < 4; ++r) {
        int row = wm + i * 16 + quad * 4 + r;          // 0..127 local
        int colL = wn + j * 16 + (lane & 15);          // 0..127 local (k of mini-GEMM)
        float v = acc[i][j][r] + b1[n0 + colL];
        v = fmaxf(v, 0.f);
        u32 f = (u32)(m0 + row) * 512u + (u32)(n0 + colL);
        u32 keep = (mask[f >> 5] >> (f & 31u)) & 1u;
        v = keep ? v * 2.f : 0.f;
        us hi, lo; splitbf(v, hi, lo);
        int slab = colL >> 6, k2 = colL & 63;
        int chunk = ((k2 >> 3) ^ (row & 7));
        int a = slab * 8192 + row * 64 + chunk * 8 + (k2 & 7);
        sHh[a] = hi; sHl[a] = lo;
      }
  __syncthreads();
  // ---- mini-GEMM: partial_logits[128][80] = h_tile[128][128] @ w2[n0:n0+128][80], bf16x3 ----
  int wm2 = wv * 32;
  f32x4 accm[2][5] = {};
#pragma unroll
  for (int ks = 0; ks < 4; ++ks) {
    int slab = ks >> 1;
    short8 a_h[2], a_l[2];
#pragma unroll
    for (int mf = 0; mf < 2; ++mf) {
      int crow = wm2 + mf * 16 + frow;
      int cm = ((((ks & 1) * 4 + fq) ^ (frow & 7))) * 8;
      int a = slab * 8192 + crow * 64 + cm;
      a_h[mf] = *(const short8*)&sHh[a];
      a_l[mf] = *(const short8*)&sHl[a];
    }
#pragma unroll
    for (int fn = 0; fn < 5; ++fn) {
      int c = fn * 16 + frow;
      size_t bo = (size_t)c * 512 + n0 + ks * 32 + fq * 8;
      short8 b_h = *(const short8*)(W2h_ + bo);
      short8 b_l = *(const short8*)(W2l_ + bo);
#pragma unroll
      for (int mf = 0; mf < 2; ++mf) {
        accm[mf][fn] = MFMA16(a_h[mf], b_h, accm[mf][fn]);
        accm[mf][fn] = MFMA16(a_h[mf], b_l, accm[mf][fn]);
        accm[mf][fn] = MFMA16(a_l[mf], b_h, accm[mf][fn]);
      }
    }
  }
#pragma unroll
  for (int mf = 0; mf < 2; ++mf)
#pragma unroll
    for (int fn = 0; fn < 5; ++fn)
#pragma unroll
      for (int r = 0; r < 4; ++r) {
        int grow = m0 + wm2 + mf * 16 + quad * 4 + r;
        int c = fn * 16 + (lane & 15);
        logitsP[((size_t)bn * 16384 + grow) * 80 + c] = accm[mf][fn][r];
      }
}

// ================= softmax: reduce 4 partials, +b2, stats, preds, hist, logp =================
__global__ __launch_bounds__(256) void k_softmax(
    const float* __restrict__ logitsP, const float* __restrict__ b2,
    float* __restrict__ logp, int* __restrict__ preds,
    float* __restrict__ accs /* [0] ent, [2..] mp */, int* __restrict__ cnt) {
  __shared__ float slog[64 * 81];
  __shared__ float sm[64], sl[64];
  __shared__ float sred[256];
  __shared__ int hh[65];
  int tid = threadIdx.x;
  int m0 = blockIdx.x * 64;
  int r = tid >> 2, cg = tid & 3;
  const float* p0 = logitsP + (size_t)(m0 + r) * 80;
#pragma unroll
  for (int cc = 0; cc < 5; ++cc) {
    int c = cg * 20 + cc * 4;
    f32x4 v = *(const f32x4*)(p0 + c);
    v += *(const f32x4*)(p0 + 16384ull * 80 + c);
    v += *(const f32x4*)(p0 + 2ull * 16384 * 80 + c);
    v += *(const f32x4*)(p0 + 3ull * 16384 * 80 + c);
#pragma unroll
    for (int e = 0; e < 4; ++e) {
      int c2 = c + e;
      if (c2 < 65) slog[r * 81 + c2] = v[e] + b2[c2];
    }
  }
  if (tid < 65) hh[tid] = 0;
  __syncthreads();
  if (tid < 64) {
    int row = tid;
    float m = -1e30f; int am = 0;
    for (int c = 0; c < 65; ++c) {
      float v = slog[row * 81 + c];
      if (v > m) { m = v; am = c; }   // first-max: strict >
    }
    float s = 0.f;
    for (int c = 0; c < 65; ++c) s += expf(slog[row * 81 + c] - m);
    sm[row] = m; sl[row] = logf(s);
    preds[m0 + row] = am;
    atomicAdd(&hh[am], 1);
  }
  __syncthreads();
  if (tid < 65 && hh[tid] > 0) atomicAdd(&cnt[tid], hh[tid]);
  float entp = 0.f;
  if (tid < 240) {
    int c = tid % 80, rr0 = tid / 80;
    if (c < 65) {
      float mpp = 0.f;
      for (int rr = rr0; rr < 64; rr += 3) {
        float v = slog[rr * 81 + c] - sm[rr] - sl[rr];
        logp[(size_t)(m0 + rr) * 65 + c] = v;
        float p = expf(v);
        mpp += p;
        entp += p * logf(p + 1e-6f);
      }
      atomicAdd(&accs[2 + c], mpp);
    }
  }
  sred[tid] = entp;
  __syncthreads();
  for (int s = 128; s > 0; s >>= 1) { if (tid < s) sred[tid] += sred[tid + s]; __syncthreads(); }
  if (tid == 0) atomicAdd(&accs[0], sred[0]);
}

// ================= scatter row indices grouped by class (local prefix scan inside) =================
__global__ __launch_bounds__(256) void k_scatter(
    const int* __restrict__ preds, const int* __restrict__ cnt,
    int* __restrict__ cursor, int* __restrict__ rowidx) {
  __shared__ int h[65];      // per-block per-class count
  __shared__ int gb[65];     // per-block reserved global offset
  __shared__ int sbase[65];  // exclusive prefix of cnt
  int tid = threadIdx.x;
  if (tid < 65) { h[tid] = 0; sbase[tid] = cnt[tid]; }
  __syncthreads();
  int i = blockIdx.x * 256 + tid;
  int c = preds[i];
  int pos = atomicAdd(&h[c], 1);     // rank within block for this class
  if (tid == 0) {
    int s = 0;
    for (int cc = 0; cc < 65; ++cc) { int v = sbase[cc]; sbase[cc] = s; s += v; }
  }
  __syncthreads();
  if (tid < 65 && h[tid] > 0) gb[tid] = atomicAdd(&cursor[tid], h[tid]);
  __syncthreads();
  rowidx[sbase[c] + gb[c] + pos] = i;
}

// ================= segment sums: gather rows per class, register accumulate =================
__global__ __launch_bounds__(256) void k_segsum2(
    const float* __restrict__ feat, const int* __restrict__ rowidx,
    const int* __restrict__ cnt,
    float* __restrict__ psum /* [16][65][2048] */) {
  int c = blockIdx.x;   // 0..64
  int j = blockIdx.y;   // 0..15
  int tid = threadIdx.x;
  int start = 0;
  for (int cc = 0; cc < 65; ++cc) { if (cc == c) break; start += cnt[cc]; }
  int n = cnt[c];
  f32x4 a0 = {}, a1 = {};
  const float* fp = feat + (size_t)tid * 8;
  for (int i = j; i < n; i += 16) {
    int row = rowidx[start + i];
    const f32x4* p = (const f32x4*)(fp + (size_t)row * 2048);
    a0 += p[0];
    a1 += p[1];
  }
  float* o = psum + ((size_t)(j * 65 + c)) * 2048 + (size_t)tid * 8;
  *(f32x4*)o = a0;
  *(f32x4*)(o + 4) = a1;
}

// ================= centroids: reduce partials, normalize, split bf16; B^T layout [80][2048] =================
__global__ __launch_bounds__(256) void k_centroid(
    const float* __restrict__ psum, const int* __restrict__ pcnt,
    us* __restrict__ ch, us* __restrict__ cl) {
  int c = blockIdx.x;  // 0..79
  int tid = threadIdx.x;
  if (c >= 65) {
    for (int d = tid; d < 2048; d += 256) { ch[(size_t)c * 2048 + d] = 0; cl[(size_t)c * 2048 + d] = 0; }
    return;
  }
  int cnt = pcnt[c];
  float inv = 1.0f / (float)((cnt > 1) ? cnt : 1);
  float mean[8]; float sq = 0.f;
  for (int i = 0; i < 8; ++i) {
    int d = tid + i * 256;
    float s = 0.f;
    for (int nc = 0; nc < 16; ++nc) s += psum[((size_t)nc * 65 + c) * 2048 + d];
    mean[i] = s * inv;
    sq += mean[i] * mean[i];
  }
  __shared__ float red[256];
  red[tid] = sq; __syncthreads();
  for (int s = 128; s > 0; s >>= 1) { if (tid < s) red[tid] += red[tid + s]; __syncthreads(); }
  float norm = sqrtf(red[0]);
  float dscale = (cnt > 0) ? 1.0f / fmaxf(norm, 1e-12f) : 0.0f;
  for (int i = 0; i < 8; ++i) {
    int d = tid + i * 256;
    us hi, lo; splitbf(mean[i] * dscale, hi, lo);
    ch[(size_t)c * 2048 + d] = hi; cl[(size_t)c * 2048 + d] = lo;
  }
}

// ================= sim GEMM (64x80, K split in 4x512, BK=64) -> partial sims =================
__global__ __launch_bounds__(256, 2) void k_sim(
    const us* __restrict__ Ah_, const us* __restrict__ Al_,   // feat planes [16384][2048]
    const us* __restrict__ Bh_, const us* __restrict__ Bl_,   // cent planes [80][2048]
    float* __restrict__ simbuf /* [4][16384][80] */) {
  __shared__ __align__(16) us sA[2][4096];
  __shared__ __align__(16) us sB[2][5120];
  int tid = threadIdx.x;
  int m0 = blockIdx.x * 64;
  int ks = blockIdx.y;             // K quarter
  int kbase = ks * 512;
  int lane = tid & 63, wv = tid >> 6;
  int frow = lane & 15, fq = lane >> 4;
  int srow = tid >> 3;
  int scolsw = (((tid & 7) ^ ((tid >> 3) & 7)) * 8);
  f32x4 acc[5] = {};
  size_t arow = (size_t)(m0 + srow) * 2048 + kbase + scolsw;
  size_t brow = (size_t)srow * 2048 + kbase + scolsw;
  size_t brow2 = (size_t)(64 + (tid >> 3)) * 2048 + kbase + scolsw;
  for (int kt = 0; kt < 8; ++kt) {
    int k0 = kt * 64;
    __syncthreads();
#pragma unroll
    for (int j = 0; j < 2; ++j) {
      int lo = j * 2048 + wv * 512;
      size_t go = (size_t)j * 32 * 2048 + k0;
      GLD16(&sA[0][lo], Ah_ + arow + go);
      GLD16(&sA[1][lo], Al_ + arow + go);
      GLD16(&sB[0][lo], Bh_ + brow + go);
      GLD16(&sB[1][lo], Bl_ + brow + go);
    }
    if (wv < 2) {
      GLD16(&sB[0][4096 + wv * 512], Bh_ + brow2 + k0);
      GLD16(&sB[1][4096 + wv * 512], Bl_ + brow2 + k0);
    }
    __syncthreads();
#pragma unroll
    for (int s = 0; s < 2; ++s) {
      int ca = ((s * 4 + fq) ^ (frow & 7)) * 8;
      short8 a_h = *(const short8*)&sA[0][(wv * 16 + frow) * 64 + ca];
      short8 a_l = *(const short8*)&sA[1][(wv * 16 + frow) * 64 + ca];
#pragma unroll
      for (int fn = 0; fn < 5; ++fn) {
        short8 b_h = *(const short8*)&sB[0][(fn * 16 + frow) * 64 + ca];
        short8 b_l = *(const short8*)&sB[1][(fn * 16 + frow) * 64 + ca];
        acc[fn] = MFMA16(a_h, b_h, acc[fn]);
        acc[fn] = MFMA16(a_h, b_l, acc[fn]);
        acc[fn] = MFMA16(a_l, b_h, acc[fn]);
      }
    }
  }
#pragma unroll
  for (int fn = 0; fn < 5; ++fn) {
    int col = fn * 16 + (lane & 15);
#pragma unroll
    for (int r = 0; r < 4; ++r) {
      int row = wv * 16 + (lane >> 4) * 4 + r;
      simbuf[((size_t)(ks * 16384 + m0 + row)) * 80 + col] = acc[fn][r];
    }
  }
}

// ================= sim reduce + CE gather + (last block) final combine =================
__global__ __launch_bounds__(256) void k_simred(
    const float* __restrict__ simbuf, const float* __restrict__ logp,
    float* __restrict__ accs, int* __restrict__ done, float* __restrict__ out) {
  __shared__ float sred[256];
  __shared__ int lastflag;
  int tid = threadIdx.x;
  int row = blockIdx.x * 256 + tid;
  const float* p0 = simbuf + (size_t)row * 80;
  float m = -1e30f; int am = 0;
  for (int c = 0; c < 65; ++c) {
    float v = p0[c] + p0[16384ull * 80 + c] + p0[2ull * 16384 * 80 + c] + p0[3ull * 16384 * 80 + c];
    if (v > m) { m = v; am = c; }   // first-max: strict >
  }
  sred[tid] = logp[(size_t)row * 65 + am];
  __syncthreads();
  for (int s = 128; s > 0; s >>= 1) { if (tid < s) sred[tid] += sred[tid + s]; __syncthreads(); }
  if (tid == 0) {
    atomicAdd(&accs[1], sred[0]);
    __threadfence();
    int old = atomicAdd(done, 1);
    lastflag = (old == 63);
  }
  __syncthreads();
  if (!lastflag) return;
  // last block: final combine. All accs reads via device-scope atomic RMW (cross-XCD safe).
  float d = 0.f;
  if (tid < 65) {
    float mp = atomicAdd(&accs[2 + tid], 0.f) * (1.f / 16384.f);
    d = mp * logf(mp + 1e-6f);
  }
  sred[tid] = d;
  __syncthreads();
  for (int s = 128; s > 0; s >>= 1) { if (tid < s) sred[tid] += sred[tid + s]; __syncthreads(); }
  if (tid == 0) {
    float entropy = -atomicAdd(&accs[0], 0.f) * (1.f / 16384.f);
    float ce = -atomicAdd(&accs[1], 0.f) * (1.f / 16384.f);
    out[0] = entropy + sred[0] + 0.3f * ce;
  }
}

extern "C" void kernel_launch(void* const* d_in, const int* in_sizes, int n_in,
                              void* d_out, int out_size, void* d_ws, size_t ws_size,
                              hipStream_t stream) {
  const float* feat = (const float*)d_in[0];
  const float* w1   = (const float*)d_in[1];
  const float* b1   = (const float*)d_in[2];
  const float* w2   = (const float*)d_in[3];
  const float* b2   = (const float*)d_in[4];
  float* out = (float*)d_out;

  char* w = (char*)d_ws;
  auto alloc = [&](size_t b) { char* p = w; w += (b + 255) & ~(size_t)255; return p; };
  us*  feat_hi = (us*)alloc(16384ull * 2048 * 2);
  us*  feat_lo = (us*)alloc(16384ull * 2048 * 2);
  us*  w1t_hi  = (us*)alloc(512ull * 2048 * 2);
  us*  w1t_lo  = (us*)alloc(512ull * 2048 * 2);
  us*  w2t_hi  = (us*)alloc(80ull * 512 * 2);
  us*  w2t_lo  = (us*)alloc(80ull * 512 * 2);
  u32* mask    = (u32*)alloc(262144ull * 4);
  float* logitsP = (float*)alloc(4ull * 16384 * 80 * 4);
  float* logp  = (float*)alloc(16384ull * 65 * 4);
  int*   preds = (int*)alloc(16384ull * 4);
  float* psum  = (float*)alloc(16ull * 65 * 2048 * 4);
  int*   cnt   = (int*)alloc(65ull * 4);
  int*   cursor= (int*)alloc(65ull * 4);
  int*   rowidx= (int*)alloc(16384ull * 4);
  us*  cent_hi = (us*)alloc(80ull * 2048 * 2);
  us*  cent_lo = (us*)alloc(80ull * 2048 * 2);
  float* simbuf= (float*)alloc(4ull * 16384 * 80 * 4);
  float* accs  = (float*)alloc(68ull * 4);
  int*   done  = (int*)alloc(4ull);

  k_prep<<<17233, 256, 0, stream>>>(feat, w1, w2, feat_hi, feat_lo,
                                    w1t_hi, w1t_lo, w2t_hi, w2t_lo,
                                    mask, accs, cnt, cursor, done);
  k_gemm1<<<dim3(128, 4), 256, 0, stream>>>(feat_hi, feat_lo, w1t_hi, w1t_lo, b1, mask,
                                            w2t_hi, w2t_lo, logitsP);
  k_softmax<<<256, 256, 0, stream>>>(logitsP, b2, logp, preds, accs, cnt);
  k_scatter<<<64, 256, 0, stream>>>(preds, cnt, cursor, rowidx);
  k_segsum2<<<dim3(65, 16), 256, 0, stream>>>(feat, rowidx, cnt, psum);
  k_centroid<<<80, 256, 0, stream>>>(psum, cnt, cent_hi, cent_lo);
  k_sim<<<dim3(256, 4), 256, 0, stream>>>(feat_hi, feat_lo, cent_hi, cent_lo, simbuf);
  k_simred<<<64, 256, 0, stream>>>(simbuf, logp, accs, done, out);
}